// Round 10
// baseline (521.049 us; speedup 1.0000x reference)
//
#include <hip/hip_runtime.h>
#include <hip/hip_fp16.h>

#define N_NODES 100000
#define N_EDGES 3200000
#define N_PAD   100096
#define BNODES  128
#define NBUCK   ((N_NODES + BNODES - 1) / BNODES)       // 782
#define BCAP    4800                                    // mean 4096, sigma 64 (11 sigma)
#define EPB_BIN 8192                                    // edges per bin block (32/thread)
#define BIN_BLOCKS ((N_EDGES + EPB_BIN - 1) / EPB_BIN)  // 391
#define SPILL_MAX 65536
#define WQSCALE  32767.0f
#define SCAN_CHUNK 2048
#define SCAN_BLOCKS ((N_NODES + SCAN_CHUNK - 1) / SCAN_CHUNK)

typedef unsigned int uint;

#define COMPILER_BARRIER() __asm__ volatile("" ::: "memory")

// ===================== fast path: bin -> sort -> nrm -> gather =====================

// prologue: x -> fp16, zero bucket_cnt/spill_cnt
__global__ __launch_bounds__(256) void k_pre(const float* __restrict__ x,
                                             __half* __restrict__ x16,
                                             int* __restrict__ bucket_cnt,
                                             int* __restrict__ spill_cnt) {
    int i = blockIdx.x * blockDim.x + threadIdx.x;
    if (i < N_NODES * 16) x16[i] = __float2half(x[i]);
    if (i < NBUCK) bucket_cnt[i] = 0;
    if (i == 0) *spill_cnt = 0;
}

// counting-sort edges into 782 dst-buckets; entry = { (dstl<<17)|src , w_bits }
__global__ __launch_bounds__(256) void k_bin(const int* __restrict__ src,
                                             const int* __restrict__ dst,
                                             const float* __restrict__ w,
                                             int* __restrict__ bucket_cnt,
                                             uint2* __restrict__ ebuf,
                                             int4* __restrict__ sp,
                                             int* __restrict__ spill_cnt) {
    __shared__ int hist[NBUCK];
    __shared__ int base[NBUCK];
    __shared__ int rank[NBUCK];
    int tid = threadIdx.x;
    for (int b = tid; b < NBUCK; b += 256) { hist[b] = 0; rank[b] = 0; }
    __syncthreads();
    int e0 = blockIdx.x * EPB_BIN;
#pragma unroll 4
    for (int k = 0; k < 32; k++) {
        int e = e0 + tid + k * 256;
        if (e < N_EDGES) atomicAdd(&hist[__builtin_nontemporal_load(dst + e) >> 7], 1);
    }
    __syncthreads();
    for (int b = tid; b < NBUCK; b += 256) {
        int c = hist[b];
        base[b] = c ? atomicAdd(&bucket_cnt[b], c) : 0;
    }
    __syncthreads();
#pragma unroll 4
    for (int k = 0; k < 32; k++) {
        int e = e0 + tid + k * 256;
        if (e < N_EDGES) {
            int s = __builtin_nontemporal_load(src + e);
            int d = __builtin_nontemporal_load(dst + e);
            float wv = __builtin_nontemporal_load(w + e);
            int b = d >> 7;
            int r = atomicAdd(&rank[b], 1);
            int pos = base[b] + r;
            if (pos < BCAP) {
                ebuf[(size_t)b * BCAP + pos] =
                    make_uint2(((uint)(d & 127) << 17) | (uint)s, __float_as_uint(wv));
            } else {
                int oi = atomicAdd(spill_cnt, 1);
                if (oi < SPILL_MAX) sp[oi] = make_int4(s, d, __float_as_int(wv), 0);
            }
        }
    }
}

// per-bucket: stage in LDS, node-histogram + weighted degree, prefix, scatter to
// node-major 4B entries (overlaying the bucket's own ebuf region), write dinv/rowptr.
__global__ __launch_bounds__(256) void k_sort(uint2* __restrict__ ebuf,
                                              const int* __restrict__ bucket_cnt,
                                              const int4* __restrict__ sp,
                                              const int* __restrict__ spill_cnt,
                                              float* __restrict__ dinv,
                                              int* __restrict__ row_beg,
                                              int* __restrict__ row_cnt) {
    __shared__ uint2 ent[BCAP];          // 38.4 KB
    __shared__ float wacc[BNODES];
    __shared__ int   hist[BNODES];
    __shared__ int   pref[BNODES];
    __shared__ int   curs[BNODES];
    int b = blockIdx.x, tid = threadIdx.x;
    int lo = b * BNODES;
    int n = N_NODES - lo; if (n > BNODES) n = BNODES;
    if (tid < BNODES) { wacc[tid] = 0.0f; hist[tid] = 0; }
    __syncthreads();
    int cnt = bucket_cnt[b]; if (cnt > BCAP) cnt = BCAP;
    const uint2* srcrow = ebuf + (size_t)b * BCAP;
    for (int j = tid; j < cnt; j += 256) {
        uint2 e = srcrow[j];
        ent[j] = e;
        int nl = e.x >> 17;
        atomicAdd(&hist[nl], 1);
        atomicAdd(&wacc[nl], __uint_as_float(e.y));
    }
    int ns = *spill_cnt; if (ns > SPILL_MAX) ns = SPILL_MAX;
    for (int i = tid; i < ns; i += 256) {
        int4 q = sp[i];
        if ((q.y >> 7) == b) atomicAdd(&wacc[q.y & 127], __int_as_float(q.z));
    }
    __syncthreads();
    // inclusive prefix over hist -> pref
    if (tid < BNODES) pref[tid] = hist[tid];
    __syncthreads();
    for (int off = 1; off < BNODES; off <<= 1) {
        int v = 0;
        if (tid < BNODES && tid >= off) v = pref[tid - off];
        __syncthreads();
        if (tid < BNODES) pref[tid] += v;
        __syncthreads();
    }
    if (tid < BNODES) curs[tid] = pref[tid] - hist[tid];   // exclusive start
    if (tid < n) {
        row_beg[lo + tid] = b * (BCAP * 2) + (pref[tid] - hist[tid]);
        row_cnt[lo + tid] = hist[tid];
        dinv[lo + tid] = rsqrtf(1.0f + wacc[tid]);
    }
    __syncthreads();
    // scatter node-sorted 4B entries over the bucket's own region (source is in LDS)
    uint* outb = (uint*)ebuf + (size_t)b * (BCAP * 2);
    for (int j = tid; j < cnt; j += 256) {
        uint2 e = ent[j];
        int nl = e.x >> 17;
        int pos = atomicAdd(&curs[nl], 1);
        uint wq = __float2uint_rn(__uint_as_float(e.y) * WQSCALE);
        outb[pos] = (wq << 17) | (e.x & 0x1FFFF);
    }
}

// fold dinv[src] into each sorted entry: q15(w) -> q15(dinv[s]*w)
__global__ __launch_bounds__(256) void k_nrm(uint* __restrict__ sbuf,
                                             const int* __restrict__ bucket_cnt,
                                             const float* __restrict__ dinv) {
    int b = blockIdx.x, tid = threadIdx.x;
    int cnt = bucket_cnt[b]; if (cnt > BCAP) cnt = BCAP;
    uint* outb = sbuf + (size_t)b * (BCAP * 2);
    for (int j = tid; j < cnt; j += 256) {
        uint e = outb[j];
        int s = e & 0x1FFFF;
        float wv = (float)(e >> 17) * (1.0f / WQSCALE);
        uint q = __float2uint_rn(dinv[s] * wv * WQSCALE);
        outb[j] = (q << 17) | (uint)s;
    }
}

// fused: layer-1 gather + self + MLP, 4 nodes per wave sequentially (16/block).
// All LDS slots are wave-private -> no __syncthreads (wave64 LDS ops are in-order).
__global__ __launch_bounds__(256) void k_gather_mlp(const uint* __restrict__ sbuf,
                                                    const int* __restrict__ row_beg,
                                                    const int* __restrict__ row_cnt,
                                                    const int4* __restrict__ sp,
                                                    const int* __restrict__ spill_cnt,
                                                    const float* __restrict__ dinv,
                                                    const __half* __restrict__ x16,
                                                    const float* __restrict__ W1,
                                                    const float* __restrict__ b1,
                                                    const float* __restrict__ W2,
                                                    const float* __restrict__ b2,
                                                    __half* __restrict__ h2,
                                                    float* __restrict__ out) {
    __shared__ float fvs[4][16];
    __shared__ float o1s[4][128];
    int wave = threadIdx.x >> 6, lane = threadIdx.x & 63;
    int node0 = blockIdx.x * 16 + wave * 4;      // 4 sequential nodes per wave
    int c2 = lane & 1, eo = lane >> 1;
    for (int it = 0; it < 4; it++) {
        int node = node0 + it;
        int beg = row_beg[node], cnt = row_cnt[node];
        float di = dinv[node];
        const uint* row = sbuf + beg;
        float acc[8];
#pragma unroll
        for (int k = 0; k < 8; k++) acc[k] = 0.0f;
        int j = eo;
        uint e = (j < cnt) ? __builtin_nontemporal_load(row + j) : 0u;
        while (j < cnt) {
            uint ec = e;
            j += 32;
            if (j < cnt) e = __builtin_nontemporal_load(row + j);   // prefetch next
            int s = ec & 0x1FFFF;
            float nq = (float)(ec >> 17) * (1.0f / WQSCALE);
            uint4 hv = *(const uint4*)(x16 + (size_t)s * 16 + c2 * 8);
            float2 f0 = __half22float2(*(__half2*)&hv.x);
            float2 f1 = __half22float2(*(__half2*)&hv.y);
            float2 f2 = __half22float2(*(__half2*)&hv.z);
            float2 f3 = __half22float2(*(__half2*)&hv.w);
            acc[0] = fmaf(nq, f0.x, acc[0]);
            acc[1] = fmaf(nq, f0.y, acc[1]);
            acc[2] = fmaf(nq, f1.x, acc[2]);
            acc[3] = fmaf(nq, f1.y, acc[3]);
            acc[4] = fmaf(nq, f2.x, acc[4]);
            acc[5] = fmaf(nq, f2.y, acc[5]);
            acc[6] = fmaf(nq, f3.x, acc[6]);
            acc[7] = fmaf(nq, f3.y, acc[7]);
        }
#pragma unroll
        for (int m = 2; m < 64; m <<= 1) {
#pragma unroll
            for (int k = 0; k < 8; k++) acc[k] += __shfl_xor(acc[k], m, 64);
        }
        if (lane < 2) {
            uint4 hv = *(const uint4*)(x16 + (size_t)node * 16 + c2 * 8);
            float2 s0 = __half22float2(*(__half2*)&hv.x);
            float2 s1 = __half22float2(*(__half2*)&hv.y);
            float2 s2 = __half22float2(*(__half2*)&hv.z);
            float2 s3 = __half22float2(*(__half2*)&hv.w);
            float slf[8] = {s0.x, s0.y, s1.x, s1.y, s2.x, s2.y, s3.x, s3.y};
            float r[8];
#pragma unroll
            for (int k = 0; k < 8; k++) r[k] = acc[k] + di * slf[k];
            int ns = *spill_cnt;                       // 0 in practice
            if (ns > 0) {
                if (ns > SPILL_MAX) ns = SPILL_MAX;
                for (int i = 0; i < ns; i++) {
                    int4 q = sp[i];
                    if (q.y == node) {
                        float f = dinv[q.x] * __int_as_float(q.z);
                        uint4 qv = *(const uint4*)(x16 + (size_t)q.x * 16 + c2 * 8);
                        float2 a0 = __half22float2(*(__half2*)&qv.x);
                        float2 a1 = __half22float2(*(__half2*)&qv.y);
                        float2 a2 = __half22float2(*(__half2*)&qv.z);
                        float2 a3 = __half22float2(*(__half2*)&qv.w);
                        r[0] += f * a0.x; r[1] += f * a0.y;
                        r[2] += f * a1.x; r[3] += f * a1.y;
                        r[4] += f * a2.x; r[5] += f * a2.y;
                        r[6] += f * a3.x; r[7] += f * a3.y;
                    }
                }
            }
#pragma unroll
            for (int k = 0; k < 8; k++) fvs[wave][c2 * 8 + k] = r[k] * di;
        }
        COMPILER_BARRIER();                 // wave-private LDS: in-order DS pipe suffices
        float fv[16];
#pragma unroll
        for (int k = 0; k < 16; k++) fv[k] = fvs[wave][k];
        float a = b1[2 * lane], bb = b1[2 * lane + 1];
#pragma unroll
        for (int k = 0; k < 16; k++) {
            float2 wv = *(const float2*)(W1 + k * 128 + 2 * lane);
            a = fmaf(fv[k], wv.x, a);
            bb = fmaf(fv[k], wv.y, bb);
        }
        o1s[wave][2 * lane + 0] = fmaxf(a, 0.0f);
        o1s[wave][2 * lane + 1] = fmaxf(bb, 0.0f);
        COMPILER_BARRIER();
        int c = lane & 15, g = lane >> 4;
        float p = 0.0f;
#pragma unroll
        for (int k = 0; k < 32; k++) {
            int kk = g * 32 + k;
            p = fmaf(o1s[wave][kk], W2[kk * 16 + c], p);
        }
        p += __shfl_down(p, 16, 64);
        p += __shfl_down(p, 32, 64);
        if (lane < 16) {
            h2[(size_t)node * 16 + c] = __float2half(p);
            out[(size_t)node * 16 + c] = di * di * p + b2[c];
        }
        COMPILER_BARRIER();                 // don't let next iter's fvs write pass o1s reads
    }
}

// layer-2 gather: out[node] += di * (sum q*h2[s] + spill); 4 nodes per wave.
__global__ __launch_bounds__(256) void k_gather2(const uint* __restrict__ sbuf,
                                                 const int* __restrict__ row_beg,
                                                 const int* __restrict__ row_cnt,
                                                 const int4* __restrict__ sp,
                                                 const int* __restrict__ spill_cnt,
                                                 const float* __restrict__ dinv,
                                                 const __half* __restrict__ h2,
                                                 float* __restrict__ out) {
    int wave = threadIdx.x >> 6, lane = threadIdx.x & 63;
    int node0 = blockIdx.x * 16 + wave * 4;
    int c2 = lane & 1, eo = lane >> 1;
    for (int it = 0; it < 4; it++) {
        int node = node0 + it;
        int beg = row_beg[node], cnt = row_cnt[node];
        float di = dinv[node];
        const uint* row = sbuf + beg;
        float acc[8];
#pragma unroll
        for (int k = 0; k < 8; k++) acc[k] = 0.0f;
        int j = eo;
        uint e = (j < cnt) ? __builtin_nontemporal_load(row + j) : 0u;
        while (j < cnt) {
            uint ec = e;
            j += 32;
            if (j < cnt) e = __builtin_nontemporal_load(row + j);
            int s = ec & 0x1FFFF;
            float nq = (float)(ec >> 17) * (1.0f / WQSCALE);
            uint4 hv = *(const uint4*)(h2 + (size_t)s * 16 + c2 * 8);
            float2 f0 = __half22float2(*(__half2*)&hv.x);
            float2 f1 = __half22float2(*(__half2*)&hv.y);
            float2 f2 = __half22float2(*(__half2*)&hv.z);
            float2 f3 = __half22float2(*(__half2*)&hv.w);
            acc[0] = fmaf(nq, f0.x, acc[0]);
            acc[1] = fmaf(nq, f0.y, acc[1]);
            acc[2] = fmaf(nq, f1.x, acc[2]);
            acc[3] = fmaf(nq, f1.y, acc[3]);
            acc[4] = fmaf(nq, f2.x, acc[4]);
            acc[5] = fmaf(nq, f2.y, acc[5]);
            acc[6] = fmaf(nq, f3.x, acc[6]);
            acc[7] = fmaf(nq, f3.y, acc[7]);
        }
#pragma unroll
        for (int m = 2; m < 64; m <<= 1) {
#pragma unroll
            for (int k = 0; k < 8; k++) acc[k] += __shfl_xor(acc[k], m, 64);
        }
        if (lane < 2) {
            int ns = *spill_cnt;
            if (ns > 0) {
                if (ns > SPILL_MAX) ns = SPILL_MAX;
                for (int i = 0; i < ns; i++) {
                    int4 q = sp[i];
                    if (q.y == node) {
                        float f = dinv[q.x] * __int_as_float(q.z);
                        uint4 qv = *(const uint4*)(h2 + (size_t)q.x * 16 + c2 * 8);
                        float2 a0 = __half22float2(*(__half2*)&qv.x);
                        float2 a1 = __half22float2(*(__half2*)&qv.y);
                        float2 a2 = __half22float2(*(__half2*)&qv.z);
                        float2 a3 = __half22float2(*(__half2*)&qv.w);
                        acc[0] += f * a0.x; acc[1] += f * a0.y;
                        acc[2] += f * a1.x; acc[3] += f * a1.y;
                        acc[4] += f * a2.x; acc[5] += f * a2.y;
                        acc[6] += f * a3.x; acc[7] += f * a3.y;
                    }
                }
            }
            float4* op = (float4*)(out + (size_t)node * 16 + c2 * 8);
            float4 o0 = op[0], o1 = op[1];
            o0.x += di * acc[0]; o0.y += di * acc[1];
            o0.z += di * acc[2]; o0.w += di * acc[3];
            o1.x += di * acc[4]; o1.y += di * acc[5];
            o1.z += di * acc[6]; o1.w += di * acc[7];
            op[0] = o0; op[1] = o1;
        }
    }
}

// ===================== CSR fallback (round-2) =====================

__global__ void k_init(float* __restrict__ deg, int* __restrict__ cnt) {
    int i = blockIdx.x * blockDim.x + threadIdx.x;
    if (i < N_NODES) { deg[i] = 1.0f; if (cnt) cnt[i] = 0; }
}

__global__ void k_degcnt(const int* __restrict__ dst, const float* __restrict__ w,
                         float* __restrict__ deg, int* __restrict__ cnt) {
    int e = blockIdx.x * blockDim.x + threadIdx.x;
    if (e < N_EDGES) {
        int d = dst[e];
        atomicAdd(&deg[d], w[e]);
        if (cnt) atomicAdd(&cnt[d], 1);
    }
}

__global__ void k_dinv_agg(const float* __restrict__ x, float* __restrict__ deg_dinv,
                           float* __restrict__ agg) {
    int i = blockIdx.x * blockDim.x + threadIdx.x;
    if (i >= N_NODES) return;
    float di = rsqrtf(deg_dinv[i]);
    deg_dinv[i] = di;
    float s = di * di;
    const float4* xr = (const float4*)(x + (size_t)i * 16);
    float4* ar = (float4*)(agg + (size_t)i * 16);
#pragma unroll
    for (int k = 0; k < 4; k++) {
        float4 v = xr[k];
        v.x *= s; v.y *= s; v.z *= s; v.w *= s;
        ar[k] = v;
    }
}

__global__ __launch_bounds__(256) void k_scan1(const int* __restrict__ cnt,
                                               int* __restrict__ rowptr,
                                               int* __restrict__ bsum) {
    __shared__ int ts[256];
    int tid = threadIdx.x;
    int base = blockIdx.x * SCAN_CHUNK + tid * 8;
    int v[8]; int s = 0;
#pragma unroll
    for (int k = 0; k < 8; k++) {
        int idx = base + k;
        v[k] = (idx < N_NODES) ? cnt[idx] : 0;
        s += v[k];
    }
    ts[tid] = s;
    __syncthreads();
    for (int off = 1; off < 256; off <<= 1) {
        int t = (tid >= off) ? ts[tid - off] : 0;
        __syncthreads();
        ts[tid] += t;
        __syncthreads();
    }
    int run = ts[tid] - s;
#pragma unroll
    for (int k = 0; k < 8; k++) {
        int idx = base + k;
        if (idx < N_NODES) rowptr[idx] = run;
        run += v[k];
    }
    if (tid == 255) bsum[blockIdx.x] = ts[255];
}

__global__ void k_scan2(int* __restrict__ bsum) {
    if (threadIdx.x == 0 && blockIdx.x == 0) {
        int run = 0;
        for (int g = 0; g < SCAN_BLOCKS; g++) { int t = bsum[g]; bsum[g] = run; run += t; }
    }
}

__global__ __launch_bounds__(256) void k_scan3(int* __restrict__ rowptr,
                                               const int* __restrict__ bsum) {
    int tid = threadIdx.x;
    int base = blockIdx.x * SCAN_CHUNK + tid * 8;
    int off = bsum[blockIdx.x];
#pragma unroll
    for (int k = 0; k < 8; k++) {
        int idx = base + k;
        if (idx < N_NODES) rowptr[idx] += off;
    }
    if (blockIdx.x == 0 && tid == 0) rowptr[N_NODES] = N_EDGES;
}

__global__ void k_fill(const int* __restrict__ src, const int* __restrict__ dst,
                       const float* __restrict__ w, const float* __restrict__ dinv,
                       const int* __restrict__ rowptr, int* __restrict__ cnt,
                       int2* __restrict__ perm) {
    int e = blockIdx.x * blockDim.x + threadIdx.x;
    if (e >= N_EDGES) return;
    int s = src[e], d = dst[e];
    float nrm = dinv[s] * w[e] * dinv[d];
    int r = atomicSub(&cnt[d], 1) - 1;
    int pos = rowptr[d] + r;
    perm[pos] = make_int2(s, __float_as_int(nrm));
}

__global__ __launch_bounds__(256) void k_gather(const int2* __restrict__ perm,
                                                const int* __restrict__ rowptr,
                                                const float* __restrict__ feat,
                                                float* __restrict__ out) {
    int wave = threadIdx.x >> 6, lane = threadIdx.x & 63;
    int node = blockIdx.x * 4 + wave;
    int c = lane & 15, eo = lane >> 4;
    int beg = rowptr[node], end = rowptr[node + 1];
    float acc = 0.0f;
    for (int j = beg + eo; j < end; j += 4) {
        int2 ed = perm[j];
        acc = fmaf(__int_as_float(ed.y), feat[(size_t)ed.x * 16 + c], acc);
    }
    acc += __shfl_xor(acc, 16, 64);
    acc += __shfl_xor(acc, 32, 64);
    if (lane < 16) out[(size_t)node * 16 + c] += acc;
}

__global__ __launch_bounds__(256) void k_mlp(float* __restrict__ agg,
                                             const float* __restrict__ W1,
                                             const float* __restrict__ b1,
                                             const float* __restrict__ W2,
                                             const float* __restrict__ b2,
                                             const float* __restrict__ dinv,
                                             float* __restrict__ out) {
    __shared__ float o1s[4][128];
    int wave = threadIdx.x >> 6;
    int lane = threadIdx.x & 63;
    int node = blockIdx.x * 4 + wave;
    const float* f = agg + (size_t)node * 16;
    float fv[16];
#pragma unroll
    for (int k = 0; k < 4; k++) {
        float4 v = ((const float4*)f)[k];
        fv[4 * k + 0] = v.x; fv[4 * k + 1] = v.y; fv[4 * k + 2] = v.z; fv[4 * k + 3] = v.w;
    }
    float a = b1[2 * lane], b = b1[2 * lane + 1];
#pragma unroll
    for (int k = 0; k < 16; k++) {
        float2 wv = *(const float2*)(W1 + k * 128 + 2 * lane);
        a = fmaf(fv[k], wv.x, a);
        b = fmaf(fv[k], wv.y, b);
    }
    o1s[wave][2 * lane + 0] = fmaxf(a, 0.0f);
    o1s[wave][2 * lane + 1] = fmaxf(b, 0.0f);
    __syncthreads();
    int c = lane & 15, g = lane >> 4;
    float p = 0.0f;
#pragma unroll
    for (int k = 0; k < 32; k++) {
        int kk = g * 32 + k;
        p = fmaf(o1s[wave][kk], W2[kk * 16 + c], p);
    }
    p += __shfl_down(p, 16, 64);
    p += __shfl_down(p, 32, 64);
    __syncthreads();
    if (lane < 16) {
        float h2v = p;
        agg[(size_t)node * 16 + c] = h2v;
        float di = dinv[node];
        out[(size_t)node * 16 + c] = di * di * h2v + b2[c];
    }
}

__global__ void k_scatter(const int* __restrict__ src, const int* __restrict__ dst,
                          const float* __restrict__ w, const float* __restrict__ dinv,
                          const float* __restrict__ feat, float* __restrict__ out) {
    int t = blockIdx.x * blockDim.x + threadIdx.x;
    int e = t >> 2;
    int c4 = (t & 3) * 4;
    if (e >= N_EDGES) return;
    int s = src[e], d = dst[e];
    float nrm = dinv[s] * w[e] * dinv[d];
    float4 v = *(const float4*)(feat + (size_t)s * 16 + c4);
    float* o = out + (size_t)d * 16 + c4;
    atomicAdd(o + 0, nrm * v.x);
    atomicAdd(o + 1, nrm * v.y);
    atomicAdd(o + 2, nrm * v.z);
    atomicAdd(o + 3, nrm * v.w);
}

// ===================== launch =====================

extern "C" void kernel_launch(void* const* d_in, const int* in_sizes, int n_in,
                              void* d_out, int out_size, void* d_ws, size_t ws_size,
                              hipStream_t stream) {
    const float* x  = (const float*)d_in[0];
    const int*   ei = (const int*)d_in[1];
    const float* w  = (const float*)d_in[2];
    const float* W1 = (const float*)d_in[3];
    const float* b1 = (const float*)d_in[4];
    const float* W2 = (const float*)d_in[5];
    const float* b2 = (const float*)d_in[6];
    float* out = (float*)d_out;

    const int* src = ei;
    const int* dst = ei + N_EDGES;
    const int B = 256;

    // ---- fast-path workspace layout (16B-aligned blocks) ----
    char* p = (char*)d_ws;
    int*    bucket_cnt = (int*)p;        p += (size_t)((NBUCK + 3) & ~3) * 4;
    int*    spill_cnt  = (int*)p;        p += 16;
    float*  dinv       = (float*)p;      p += (size_t)N_PAD * 4;
    int*    row_beg    = (int*)p;        p += (size_t)N_PAD * 4;
    int*    row_cnt    = (int*)p;        p += (size_t)N_PAD * 4;
    __half* x16        = (__half*)p;     p += (size_t)N_NODES * 16 * 2;
    __half* h2         = (__half*)p;     p += (size_t)N_NODES * 16 * 2;
    int4*   sp         = (int4*)p;       p += (size_t)SPILL_MAX * 16;
    uint2*  ebuf       = (uint2*)p;      p += (size_t)NBUCK * BCAP * 8;
    const size_t WS_FAST = (size_t)(p - (char*)d_ws);

    if (ws_size >= WS_FAST) {
        k_pre<<<(N_NODES * 16 + B - 1) / B, B, 0, stream>>>(x, x16, bucket_cnt, spill_cnt);
        k_bin<<<BIN_BLOCKS, B, 0, stream>>>(src, dst, w, bucket_cnt, ebuf, sp, spill_cnt);
        k_sort<<<NBUCK, B, 0, stream>>>(ebuf, bucket_cnt, sp, spill_cnt,
                                        dinv, row_beg, row_cnt);
        k_nrm<<<NBUCK, B, 0, stream>>>((uint*)ebuf, bucket_cnt, dinv);
        k_gather_mlp<<<N_NODES / 16, B, 0, stream>>>((const uint*)ebuf, row_beg, row_cnt,
                                                     sp, spill_cnt, dinv, x16,
                                                     W1, b1, W2, b2, h2, out);
        k_gather2<<<N_NODES / 16, B, 0, stream>>>((const uint*)ebuf, row_beg, row_cnt,
                                                  sp, spill_cnt, dinv, h2, out);
        return;
    }

    // ---- CSR fallback (round-2 path) ----
    float* deg_dinv = (float*)d_ws;
    int*   cntb     = (int*)(deg_dinv + N_PAD);
    int*   rowptr   = cntb + N_PAD;
    int*   bsum     = rowptr + N_PAD;
    float* agg      = (float*)(bsum + 64);
    int2*  perm     = (int2*)(agg + (size_t)N_NODES * 16);
    const size_t WS_CSR = ((size_t)N_PAD * 3 + 64 + (size_t)N_NODES * 16) * 4
                          + (size_t)N_EDGES * 8;

    if (ws_size >= WS_CSR) {
        k_init<<<(N_NODES + B - 1) / B, B, 0, stream>>>(deg_dinv, cntb);
        k_degcnt<<<(N_EDGES + B - 1) / B, B, 0, stream>>>(dst, w, deg_dinv, cntb);
        k_dinv_agg<<<(N_NODES + B - 1) / B, B, 0, stream>>>(x, deg_dinv, agg);
        k_scan1<<<SCAN_BLOCKS, 256, 0, stream>>>(cntb, rowptr, bsum);
        k_scan2<<<1, 64, 0, stream>>>(bsum);
        k_scan3<<<SCAN_BLOCKS, 256, 0, stream>>>(rowptr, bsum);
        k_fill<<<(N_EDGES + B - 1) / B, B, 0, stream>>>(src, dst, w, deg_dinv,
                                                        rowptr, cntb, perm);
        k_gather<<<N_NODES / 4, B, 0, stream>>>(perm, rowptr, x, agg);
        k_mlp<<<N_NODES / 4, B, 0, stream>>>(agg, W1, b1, W2, b2, deg_dinv, out);
        k_gather<<<N_NODES / 4, B, 0, stream>>>(perm, rowptr, agg, out);
    } else {
        float* deg = (float*)d_ws;
        float* ag  = (float*)d_ws + N_NODES;
        k_init<<<(N_NODES + B - 1) / B, B, 0, stream>>>(deg, (int*)nullptr);
        k_degcnt<<<(N_EDGES + B - 1) / B, B, 0, stream>>>(dst, w, deg, (int*)nullptr);
        k_dinv_agg<<<(N_NODES + B - 1) / B, B, 0, stream>>>(x, deg, ag);
        k_scatter<<<((size_t)N_EDGES * 4 + B - 1) / B, B, 0, stream>>>(src, dst, w, deg, x, ag);
        k_mlp<<<N_NODES / 4, B, 0, stream>>>(ag, W1, b1, W2, b2, deg, out);
        k_scatter<<<((size_t)N_EDGES * 4 + B - 1) / B, B, 0, stream>>>(src, dst, w, deg, ag, out);
    }
}

// Round 11
// 391.354 us; speedup vs baseline: 1.3314x; 1.3314x over previous
//
#include <hip/hip_runtime.h>
#include <hip/hip_fp16.h>

#define N_NODES 100000
#define N_EDGES 3200000
#define N_PAD   100096
#define BNODES  128
#define NBUCK   ((N_NODES + BNODES - 1) / BNODES)       // 782
#define BCAP    4800                                    // mean 4096, sigma 64 (11 sigma)
#define EPB_BIN 8192                                    // edges per bin block (32/thread)
#define BIN_BLOCKS ((N_EDGES + EPB_BIN - 1) / EPB_BIN)  // 391
#define SPILL_MAX 65536
#define WQSCALE  32767.0f
#define SCAN_CHUNK 2048
#define SCAN_BLOCKS ((N_NODES + SCAN_CHUNK - 1) / SCAN_CHUNK)

typedef unsigned int uint;

// ===================== fast path: bin -> sort -> nrm -> gather =====================

// prologue: x -> fp16, zero bucket_cnt/spill_cnt
__global__ __launch_bounds__(256) void k_pre(const float* __restrict__ x,
                                             __half* __restrict__ x16,
                                             int* __restrict__ bucket_cnt,
                                             int* __restrict__ spill_cnt) {
    int i = blockIdx.x * blockDim.x + threadIdx.x;
    if (i < N_NODES * 16) x16[i] = __float2half(x[i]);
    if (i < NBUCK) bucket_cnt[i] = 0;
    if (i == 0) *spill_cnt = 0;
}

// counting-sort edges into 782 dst-buckets; entry = { (dstl<<17)|src , w_bits }
__global__ __launch_bounds__(256) void k_bin(const int* __restrict__ src,
                                             const int* __restrict__ dst,
                                             const float* __restrict__ w,
                                             int* __restrict__ bucket_cnt,
                                             uint2* __restrict__ ebuf,
                                             int4* __restrict__ sp,
                                             int* __restrict__ spill_cnt) {
    __shared__ int hist[NBUCK];
    __shared__ int base[NBUCK];
    __shared__ int rank[NBUCK];
    int tid = threadIdx.x;
    for (int b = tid; b < NBUCK; b += 256) { hist[b] = 0; rank[b] = 0; }
    __syncthreads();
    int e0 = blockIdx.x * EPB_BIN;
#pragma unroll 4
    for (int k = 0; k < 32; k++) {
        int e = e0 + tid + k * 256;
        if (e < N_EDGES) atomicAdd(&hist[__builtin_nontemporal_load(dst + e) >> 7], 1);
    }
    __syncthreads();
    for (int b = tid; b < NBUCK; b += 256) {
        int c = hist[b];
        base[b] = c ? atomicAdd(&bucket_cnt[b], c) : 0;
    }
    __syncthreads();
#pragma unroll 4
    for (int k = 0; k < 32; k++) {
        int e = e0 + tid + k * 256;
        if (e < N_EDGES) {
            int s = __builtin_nontemporal_load(src + e);
            int d = __builtin_nontemporal_load(dst + e);
            float wv = __builtin_nontemporal_load(w + e);
            int b = d >> 7;
            int r = atomicAdd(&rank[b], 1);
            int pos = base[b] + r;
            if (pos < BCAP) {
                ebuf[(size_t)b * BCAP + pos] =
                    make_uint2(((uint)(d & 127) << 17) | (uint)s, __float_as_uint(wv));
            } else {
                int oi = atomicAdd(spill_cnt, 1);
                if (oi < SPILL_MAX) sp[oi] = make_int4(s, d, __float_as_int(wv), 0);
            }
        }
    }
}

// per-bucket: stage in LDS, node-histogram + weighted degree, prefix, scatter to
// node-major 4B entries (overlaying the bucket's own ebuf region); write dinv/meta.
__global__ __launch_bounds__(256) void k_sort(uint2* __restrict__ ebuf,
                                              const int* __restrict__ bucket_cnt,
                                              const int4* __restrict__ sp,
                                              const int* __restrict__ spill_cnt,
                                              float* __restrict__ dinv,
                                              int2* __restrict__ meta) {
    __shared__ uint2 ent[BCAP];          // 38.4 KB
    __shared__ float wacc[BNODES];
    __shared__ int   hist[BNODES];
    __shared__ int   pref[BNODES];
    __shared__ int   curs[BNODES];
    int b = blockIdx.x, tid = threadIdx.x;
    int lo = b * BNODES;
    int n = N_NODES - lo; if (n > BNODES) n = BNODES;
    if (tid < BNODES) { wacc[tid] = 0.0f; hist[tid] = 0; }
    __syncthreads();
    int cnt = bucket_cnt[b]; if (cnt > BCAP) cnt = BCAP;
    const uint2* srcrow = ebuf + (size_t)b * BCAP;
    for (int j = tid; j < cnt; j += 256) {
        uint2 e = srcrow[j];
        ent[j] = e;
        int nl = e.x >> 17;
        atomicAdd(&hist[nl], 1);
        atomicAdd(&wacc[nl], __uint_as_float(e.y));
    }
    int ns = *spill_cnt; if (ns > SPILL_MAX) ns = SPILL_MAX;
    for (int i = tid; i < ns; i += 256) {
        int4 q = sp[i];
        if ((q.y >> 7) == b) atomicAdd(&wacc[q.y & 127], __int_as_float(q.z));
    }
    __syncthreads();
    // inclusive prefix over hist -> pref
    if (tid < BNODES) pref[tid] = hist[tid];
    __syncthreads();
    for (int off = 1; off < BNODES; off <<= 1) {
        int v = 0;
        if (tid < BNODES && tid >= off) v = pref[tid - off];
        __syncthreads();
        if (tid < BNODES) pref[tid] += v;
        __syncthreads();
    }
    if (tid < BNODES) curs[tid] = pref[tid] - hist[tid];   // exclusive start
    if (tid < n) {
        meta[lo + tid] = make_int2(b * (BCAP * 2) + (pref[tid] - hist[tid]), hist[tid]);
        dinv[lo + tid] = rsqrtf(1.0f + wacc[tid]);
    }
    __syncthreads();
    // scatter node-sorted 4B entries over the bucket's own region (source is in LDS)
    uint* outb = (uint*)ebuf + (size_t)b * (BCAP * 2);
    for (int j = tid; j < cnt; j += 256) {
        uint2 e = ent[j];
        int nl = e.x >> 17;
        int pos = atomicAdd(&curs[nl], 1);
        uint wq = __float2uint_rn(__uint_as_float(e.y) * WQSCALE);
        outb[pos] = (wq << 17) | (e.x & 0x1FFFF);
    }
}

// fold dinv[src] into each sorted entry: q15(w) -> q15(dinv[s]*w)
__global__ __launch_bounds__(256) void k_nrm(uint* __restrict__ sbuf,
                                             const int* __restrict__ bucket_cnt,
                                             const float* __restrict__ dinv) {
    int b = blockIdx.x, tid = threadIdx.x;
    int cnt = bucket_cnt[b]; if (cnt > BCAP) cnt = BCAP;
    uint* outb = sbuf + (size_t)b * (BCAP * 2);
    for (int j = tid; j < cnt; j += 256) {
        uint e = outb[j];
        int s = e & 0x1FFFF;
        float wv = (float)(e >> 17) * (1.0f / WQSCALE);
        uint q = __float2uint_rn(dinv[s] * wv * WQSCALE);
        outb[j] = (q << 17) | (uint)s;
    }
}

// fused: layer-1 gather + self + MLP; TWO nodes per wave, interleaved loads.
// 8 nodes per block (4 waves x 2). Entry q15 = dinv[s]*w.
__global__ __launch_bounds__(256) void k_gather_mlp(const uint* __restrict__ sbuf,
                                                    const int2* __restrict__ meta,
                                                    const int4* __restrict__ sp,
                                                    const int* __restrict__ spill_cnt,
                                                    const float* __restrict__ dinv,
                                                    const __half* __restrict__ x16,
                                                    const float* __restrict__ W1,
                                                    const float* __restrict__ b1,
                                                    const float* __restrict__ W2,
                                                    const float* __restrict__ b2,
                                                    __half* __restrict__ h2,
                                                    float* __restrict__ out) {
    __shared__ float fvs[4][2][16];
    __shared__ float o1s[4][2][128];
    int wave = threadIdx.x >> 6, lane = threadIdx.x & 63;
    int nodeA = blockIdx.x * 8 + wave * 2;       // even -> meta 16B aligned
    int nodeB = nodeA + 1;
    int c2 = lane & 1, eo = lane >> 1;
    int4 mm = *(const int4*)(meta + nodeA);      // {begA,cntA,begB,cntB}
    int cntA = mm.y, cntB = mm.w;
    float diA = dinv[nodeA], diB = dinv[nodeB];
    const uint* rowA = sbuf + mm.x;
    const uint* rowB = sbuf + mm.z;
    float accA[8], accB[8];
#pragma unroll
    for (int k = 0; k < 8; k++) { accA[k] = 0.0f; accB[k] = 0.0f; }
    int total = cntA > cntB ? cntA : cntB;
    int j = eo;
    uint eA = __builtin_nontemporal_load(rowA + ((j < cntA) ? j : 0));
    uint eB = __builtin_nontemporal_load(rowB + ((j < cntB) ? j : 0));
    while (j < total) {
        bool pA = j < cntA, pB = j < cntB;
        uint ecA = eA, ecB = eB;
        int jn = j + 32;
        eA = __builtin_nontemporal_load(rowA + ((jn < cntA) ? jn : 0));   // prefetch
        eB = __builtin_nontemporal_load(rowB + ((jn < cntB) ? jn : 0));
        int sA = ecA & 0x1FFFF, sB = ecB & 0x1FFFF;
        float nqA = pA ? (float)(ecA >> 17) * (1.0f / WQSCALE) : 0.0f;
        float nqB = pB ? (float)(ecB >> 17) * (1.0f / WQSCALE) : 0.0f;
        uint4 hvA = *(const uint4*)(x16 + (size_t)sA * 16 + c2 * 8);      // both issue
        uint4 hvB = *(const uint4*)(x16 + (size_t)sB * 16 + c2 * 8);
        float2 a0 = __half22float2(*(__half2*)&hvA.x);
        float2 a1 = __half22float2(*(__half2*)&hvA.y);
        float2 a2 = __half22float2(*(__half2*)&hvA.z);
        float2 a3 = __half22float2(*(__half2*)&hvA.w);
        accA[0] = fmaf(nqA, a0.x, accA[0]); accA[1] = fmaf(nqA, a0.y, accA[1]);
        accA[2] = fmaf(nqA, a1.x, accA[2]); accA[3] = fmaf(nqA, a1.y, accA[3]);
        accA[4] = fmaf(nqA, a2.x, accA[4]); accA[5] = fmaf(nqA, a2.y, accA[5]);
        accA[6] = fmaf(nqA, a3.x, accA[6]); accA[7] = fmaf(nqA, a3.y, accA[7]);
        float2 b0 = __half22float2(*(__half2*)&hvB.x);
        float2 b1v = __half22float2(*(__half2*)&hvB.y);
        float2 b2v = __half22float2(*(__half2*)&hvB.z);
        float2 b3 = __half22float2(*(__half2*)&hvB.w);
        accB[0] = fmaf(nqB, b0.x, accB[0]); accB[1] = fmaf(nqB, b0.y, accB[1]);
        accB[2] = fmaf(nqB, b1v.x, accB[2]); accB[3] = fmaf(nqB, b1v.y, accB[3]);
        accB[4] = fmaf(nqB, b2v.x, accB[4]); accB[5] = fmaf(nqB, b2v.y, accB[5]);
        accB[6] = fmaf(nqB, b3.x, accB[6]); accB[7] = fmaf(nqB, b3.y, accB[7]);
        j = jn;
    }
#pragma unroll
    for (int m = 2; m < 64; m <<= 1) {
#pragma unroll
        for (int k = 0; k < 8; k++) {
            accA[k] += __shfl_xor(accA[k], m, 64);
            accB[k] += __shfl_xor(accB[k], m, 64);
        }
    }
    if (lane < 2) {
        // node A self + spill + scale
        uint4 hv = *(const uint4*)(x16 + (size_t)nodeA * 16 + c2 * 8);
        float2 s0 = __half22float2(*(__half2*)&hv.x);
        float2 s1 = __half22float2(*(__half2*)&hv.y);
        float2 s2 = __half22float2(*(__half2*)&hv.z);
        float2 s3 = __half22float2(*(__half2*)&hv.w);
        float slf[8] = {s0.x, s0.y, s1.x, s1.y, s2.x, s2.y, s3.x, s3.y};
        uint4 hw = *(const uint4*)(x16 + (size_t)nodeB * 16 + c2 * 8);
        float2 t0 = __half22float2(*(__half2*)&hw.x);
        float2 t1 = __half22float2(*(__half2*)&hw.y);
        float2 t2 = __half22float2(*(__half2*)&hw.z);
        float2 t3 = __half22float2(*(__half2*)&hw.w);
        float slfB[8] = {t0.x, t0.y, t1.x, t1.y, t2.x, t2.y, t3.x, t3.y};
        float rA[8], rB[8];
#pragma unroll
        for (int k = 0; k < 8; k++) {
            rA[k] = accA[k] + diA * slf[k];
            rB[k] = accB[k] + diB * slfB[k];
        }
        int ns = *spill_cnt;                       // 0 in practice
        if (ns > 0) {
            if (ns > SPILL_MAX) ns = SPILL_MAX;
            for (int i = 0; i < ns; i++) {
                int4 q = sp[i];
                if (q.y == nodeA || q.y == nodeB) {
                    float f = dinv[q.x] * __int_as_float(q.z);
                    uint4 qv = *(const uint4*)(x16 + (size_t)q.x * 16 + c2 * 8);
                    float2 u0 = __half22float2(*(__half2*)&qv.x);
                    float2 u1 = __half22float2(*(__half2*)&qv.y);
                    float2 u2 = __half22float2(*(__half2*)&qv.z);
                    float2 u3 = __half22float2(*(__half2*)&qv.w);
                    float uv[8] = {u0.x, u0.y, u1.x, u1.y, u2.x, u2.y, u3.x, u3.y};
                    if (q.y == nodeA) { for (int k = 0; k < 8; k++) rA[k] += f * uv[k]; }
                    else              { for (int k = 0; k < 8; k++) rB[k] += f * uv[k]; }
                }
            }
        }
#pragma unroll
        for (int k = 0; k < 8; k++) {
            fvs[wave][0][c2 * 8 + k] = rA[k] * diA;
            fvs[wave][1][c2 * 8 + k] = rB[k] * diB;
        }
    }
    __syncthreads();
    // GEMM1 for both nodes -> o1s
    {
        float fv[16];
#pragma unroll
        for (int k = 0; k < 16; k++) fv[k] = fvs[wave][0][k];
        float a = b1[2 * lane], bb = b1[2 * lane + 1];
#pragma unroll
        for (int k = 0; k < 16; k++) {
            float2 wv = *(const float2*)(W1 + k * 128 + 2 * lane);
            a = fmaf(fv[k], wv.x, a);
            bb = fmaf(fv[k], wv.y, bb);
        }
        o1s[wave][0][2 * lane + 0] = fmaxf(a, 0.0f);
        o1s[wave][0][2 * lane + 1] = fmaxf(bb, 0.0f);
#pragma unroll
        for (int k = 0; k < 16; k++) fv[k] = fvs[wave][1][k];
        a = b1[2 * lane]; bb = b1[2 * lane + 1];
#pragma unroll
        for (int k = 0; k < 16; k++) {
            float2 wv = *(const float2*)(W1 + k * 128 + 2 * lane);
            a = fmaf(fv[k], wv.x, a);
            bb = fmaf(fv[k], wv.y, bb);
        }
        o1s[wave][1][2 * lane + 0] = fmaxf(a, 0.0f);
        o1s[wave][1][2 * lane + 1] = fmaxf(bb, 0.0f);
    }
    __syncthreads();
    // GEMM2 for both nodes
    int c = lane & 15, g = lane >> 4;
    float pA = 0.0f, pB = 0.0f;
#pragma unroll
    for (int k = 0; k < 32; k++) {
        int kk = g * 32 + k;
        float wv = W2[kk * 16 + c];
        pA = fmaf(o1s[wave][0][kk], wv, pA);
        pB = fmaf(o1s[wave][1][kk], wv, pB);
    }
    pA += __shfl_down(pA, 16, 64);
    pA += __shfl_down(pA, 32, 64);
    pB += __shfl_down(pB, 16, 64);
    pB += __shfl_down(pB, 32, 64);
    if (lane < 16) {
        h2[(size_t)nodeA * 16 + c] = __float2half(pA);
        out[(size_t)nodeA * 16 + c] = diA * diA * pA + b2[c];
        h2[(size_t)nodeB * 16 + c] = __float2half(pB);
        out[(size_t)nodeB * 16 + c] = diB * diB * pB + b2[c];
    }
}

// layer-2 gather: out[node] += di * (sum q*h2[s] + spill); 2 nodes per wave.
__global__ __launch_bounds__(256) void k_gather2(const uint* __restrict__ sbuf,
                                                 const int2* __restrict__ meta,
                                                 const int4* __restrict__ sp,
                                                 const int* __restrict__ spill_cnt,
                                                 const float* __restrict__ dinv,
                                                 const __half* __restrict__ h2,
                                                 float* __restrict__ out) {
    int wave = threadIdx.x >> 6, lane = threadIdx.x & 63;
    int nodeA = blockIdx.x * 8 + wave * 2;
    int nodeB = nodeA + 1;
    int c2 = lane & 1, eo = lane >> 1;
    int4 mm = *(const int4*)(meta + nodeA);
    int cntA = mm.y, cntB = mm.w;
    float diA = dinv[nodeA], diB = dinv[nodeB];
    const uint* rowA = sbuf + mm.x;
    const uint* rowB = sbuf + mm.z;
    float accA[8], accB[8];
#pragma unroll
    for (int k = 0; k < 8; k++) { accA[k] = 0.0f; accB[k] = 0.0f; }
    int total = cntA > cntB ? cntA : cntB;
    int j = eo;
    uint eA = __builtin_nontemporal_load(rowA + ((j < cntA) ? j : 0));
    uint eB = __builtin_nontemporal_load(rowB + ((j < cntB) ? j : 0));
    while (j < total) {
        bool pA = j < cntA, pB = j < cntB;
        uint ecA = eA, ecB = eB;
        int jn = j + 32;
        eA = __builtin_nontemporal_load(rowA + ((jn < cntA) ? jn : 0));
        eB = __builtin_nontemporal_load(rowB + ((jn < cntB) ? jn : 0));
        int sA = ecA & 0x1FFFF, sB = ecB & 0x1FFFF;
        float nqA = pA ? (float)(ecA >> 17) * (1.0f / WQSCALE) : 0.0f;
        float nqB = pB ? (float)(ecB >> 17) * (1.0f / WQSCALE) : 0.0f;
        uint4 hvA = *(const uint4*)(h2 + (size_t)sA * 16 + c2 * 8);
        uint4 hvB = *(const uint4*)(h2 + (size_t)sB * 16 + c2 * 8);
        float2 a0 = __half22float2(*(__half2*)&hvA.x);
        float2 a1 = __half22float2(*(__half2*)&hvA.y);
        float2 a2 = __half22float2(*(__half2*)&hvA.z);
        float2 a3 = __half22float2(*(__half2*)&hvA.w);
        accA[0] = fmaf(nqA, a0.x, accA[0]); accA[1] = fmaf(nqA, a0.y, accA[1]);
        accA[2] = fmaf(nqA, a1.x, accA[2]); accA[3] = fmaf(nqA, a1.y, accA[3]);
        accA[4] = fmaf(nqA, a2.x, accA[4]); accA[5] = fmaf(nqA, a2.y, accA[5]);
        accA[6] = fmaf(nqA, a3.x, accA[6]); accA[7] = fmaf(nqA, a3.y, accA[7]);
        float2 b0 = __half22float2(*(__half2*)&hvB.x);
        float2 b1v = __half22float2(*(__half2*)&hvB.y);
        float2 b2v = __half22float2(*(__half2*)&hvB.z);
        float2 b3 = __half22float2(*(__half2*)&hvB.w);
        accB[0] = fmaf(nqB, b0.x, accB[0]); accB[1] = fmaf(nqB, b0.y, accB[1]);
        accB[2] = fmaf(nqB, b1v.x, accB[2]); accB[3] = fmaf(nqB, b1v.y, accB[3]);
        accB[4] = fmaf(nqB, b2v.x, accB[4]); accB[5] = fmaf(nqB, b2v.y, accB[5]);
        accB[6] = fmaf(nqB, b3.x, accB[6]); accB[7] = fmaf(nqB, b3.y, accB[7]);
        j = jn;
    }
#pragma unroll
    for (int m = 2; m < 64; m <<= 1) {
#pragma unroll
        for (int k = 0; k < 8; k++) {
            accA[k] += __shfl_xor(accA[k], m, 64);
            accB[k] += __shfl_xor(accB[k], m, 64);
        }
    }
    if (lane < 2) {
        int ns = *spill_cnt;
        if (ns > 0) {
            if (ns > SPILL_MAX) ns = SPILL_MAX;
            for (int i = 0; i < ns; i++) {
                int4 q = sp[i];
                if (q.y == nodeA || q.y == nodeB) {
                    float f = dinv[q.x] * __int_as_float(q.z);
                    uint4 qv = *(const uint4*)(h2 + (size_t)q.x * 16 + c2 * 8);
                    float2 u0 = __half22float2(*(__half2*)&qv.x);
                    float2 u1 = __half22float2(*(__half2*)&qv.y);
                    float2 u2 = __half22float2(*(__half2*)&qv.z);
                    float2 u3 = __half22float2(*(__half2*)&qv.w);
                    float uv[8] = {u0.x, u0.y, u1.x, u1.y, u2.x, u2.y, u3.x, u3.y};
                    if (q.y == nodeA) { for (int k = 0; k < 8; k++) accA[k] += f * uv[k]; }
                    else              { for (int k = 0; k < 8; k++) accB[k] += f * uv[k]; }
                }
            }
        }
        float4* opA = (float4*)(out + (size_t)nodeA * 16 + c2 * 8);
        float4 oa0 = opA[0], oa1 = opA[1];
        oa0.x += diA * accA[0]; oa0.y += diA * accA[1];
        oa0.z += diA * accA[2]; oa0.w += diA * accA[3];
        oa1.x += diA * accA[4]; oa1.y += diA * accA[5];
        oa1.z += diA * accA[6]; oa1.w += diA * accA[7];
        opA[0] = oa0; opA[1] = oa1;
        float4* opB = (float4*)(out + (size_t)nodeB * 16 + c2 * 8);
        float4 ob0 = opB[0], ob1 = opB[1];
        ob0.x += diB * accB[0]; ob0.y += diB * accB[1];
        ob0.z += diB * accB[2]; ob0.w += diB * accB[3];
        ob1.x += diB * accB[4]; ob1.y += diB * accB[5];
        ob1.z += diB * accB[6]; ob1.w += diB * accB[7];
        opB[0] = ob0; opB[1] = ob1;
    }
}

// ===================== CSR fallback (round-2) =====================

__global__ void k_init(float* __restrict__ deg, int* __restrict__ cnt) {
    int i = blockIdx.x * blockDim.x + threadIdx.x;
    if (i < N_NODES) { deg[i] = 1.0f; if (cnt) cnt[i] = 0; }
}

__global__ void k_degcnt(const int* __restrict__ dst, const float* __restrict__ w,
                         float* __restrict__ deg, int* __restrict__ cnt) {
    int e = blockIdx.x * blockDim.x + threadIdx.x;
    if (e < N_EDGES) {
        int d = dst[e];
        atomicAdd(&deg[d], w[e]);
        if (cnt) atomicAdd(&cnt[d], 1);
    }
}

__global__ void k_dinv_agg(const float* __restrict__ x, float* __restrict__ deg_dinv,
                           float* __restrict__ agg) {
    int i = blockIdx.x * blockDim.x + threadIdx.x;
    if (i >= N_NODES) return;
    float di = rsqrtf(deg_dinv[i]);
    deg_dinv[i] = di;
    float s = di * di;
    const float4* xr = (const float4*)(x + (size_t)i * 16);
    float4* ar = (float4*)(agg + (size_t)i * 16);
#pragma unroll
    for (int k = 0; k < 4; k++) {
        float4 v = xr[k];
        v.x *= s; v.y *= s; v.z *= s; v.w *= s;
        ar[k] = v;
    }
}

__global__ __launch_bounds__(256) void k_scan1(const int* __restrict__ cnt,
                                               int* __restrict__ rowptr,
                                               int* __restrict__ bsum) {
    __shared__ int ts[256];
    int tid = threadIdx.x;
    int base = blockIdx.x * SCAN_CHUNK + tid * 8;
    int v[8]; int s = 0;
#pragma unroll
    for (int k = 0; k < 8; k++) {
        int idx = base + k;
        v[k] = (idx < N_NODES) ? cnt[idx] : 0;
        s += v[k];
    }
    ts[tid] = s;
    __syncthreads();
    for (int off = 1; off < 256; off <<= 1) {
        int t = (tid >= off) ? ts[tid - off] : 0;
        __syncthreads();
        ts[tid] += t;
        __syncthreads();
    }
    int run = ts[tid] - s;
#pragma unroll
    for (int k = 0; k < 8; k++) {
        int idx = base + k;
        if (idx < N_NODES) rowptr[idx] = run;
        run += v[k];
    }
    if (tid == 255) bsum[blockIdx.x] = ts[255];
}

__global__ void k_scan2(int* __restrict__ bsum) {
    if (threadIdx.x == 0 && blockIdx.x == 0) {
        int run = 0;
        for (int g = 0; g < SCAN_BLOCKS; g++) { int t = bsum[g]; bsum[g] = run; run += t; }
    }
}

__global__ __launch_bounds__(256) void k_scan3(int* __restrict__ rowptr,
                                               const int* __restrict__ bsum) {
    int tid = threadIdx.x;
    int base = blockIdx.x * SCAN_CHUNK + tid * 8;
    int off = bsum[blockIdx.x];
#pragma unroll
    for (int k = 0; k < 8; k++) {
        int idx = base + k;
        if (idx < N_NODES) rowptr[idx] += off;
    }
    if (blockIdx.x == 0 && tid == 0) rowptr[N_NODES] = N_EDGES;
}

__global__ void k_fill(const int* __restrict__ src, const int* __restrict__ dst,
                       const float* __restrict__ w, const float* __restrict__ dinv,
                       const int* __restrict__ rowptr, int* __restrict__ cnt,
                       int2* __restrict__ perm) {
    int e = blockIdx.x * blockDim.x + threadIdx.x;
    if (e >= N_EDGES) return;
    int s = src[e], d = dst[e];
    float nrm = dinv[s] * w[e] * dinv[d];
    int r = atomicSub(&cnt[d], 1) - 1;
    int pos = rowptr[d] + r;
    perm[pos] = make_int2(s, __float_as_int(nrm));
}

__global__ __launch_bounds__(256) void k_gather(const int2* __restrict__ perm,
                                                const int* __restrict__ rowptr,
                                                const float* __restrict__ feat,
                                                float* __restrict__ out) {
    int wave = threadIdx.x >> 6, lane = threadIdx.x & 63;
    int node = blockIdx.x * 4 + wave;
    int c = lane & 15, eo = lane >> 4;
    int beg = rowptr[node], end = rowptr[node + 1];
    float acc = 0.0f;
    for (int j = beg + eo; j < end; j += 4) {
        int2 ed = perm[j];
        acc = fmaf(__int_as_float(ed.y), feat[(size_t)ed.x * 16 + c], acc);
    }
    acc += __shfl_xor(acc, 16, 64);
    acc += __shfl_xor(acc, 32, 64);
    if (lane < 16) out[(size_t)node * 16 + c] += acc;
}

__global__ __launch_bounds__(256) void k_mlp(float* __restrict__ agg,
                                             const float* __restrict__ W1,
                                             const float* __restrict__ b1,
                                             const float* __restrict__ W2,
                                             const float* __restrict__ b2,
                                             const float* __restrict__ dinv,
                                             float* __restrict__ out) {
    __shared__ float o1s[4][128];
    int wave = threadIdx.x >> 6;
    int lane = threadIdx.x & 63;
    int node = blockIdx.x * 4 + wave;
    const float* f = agg + (size_t)node * 16;
    float fv[16];
#pragma unroll
    for (int k = 0; k < 4; k++) {
        float4 v = ((const float4*)f)[k];
        fv[4 * k + 0] = v.x; fv[4 * k + 1] = v.y; fv[4 * k + 2] = v.z; fv[4 * k + 3] = v.w;
    }
    float a = b1[2 * lane], b = b1[2 * lane + 1];
#pragma unroll
    for (int k = 0; k < 16; k++) {
        float2 wv = *(const float2*)(W1 + k * 128 + 2 * lane);
        a = fmaf(fv[k], wv.x, a);
        b = fmaf(fv[k], wv.y, b);
    }
    o1s[wave][2 * lane + 0] = fmaxf(a, 0.0f);
    o1s[wave][2 * lane + 1] = fmaxf(b, 0.0f);
    __syncthreads();
    int c = lane & 15, g = lane >> 4;
    float p = 0.0f;
#pragma unroll
    for (int k = 0; k < 32; k++) {
        int kk = g * 32 + k;
        p = fmaf(o1s[wave][kk], W2[kk * 16 + c], p);
    }
    p += __shfl_down(p, 16, 64);
    p += __shfl_down(p, 32, 64);
    __syncthreads();
    if (lane < 16) {
        float h2v = p;
        agg[(size_t)node * 16 + c] = h2v;
        float di = dinv[node];
        out[(size_t)node * 16 + c] = di * di * h2v + b2[c];
    }
}

__global__ void k_scatter(const int* __restrict__ src, const int* __restrict__ dst,
                          const float* __restrict__ w, const float* __restrict__ dinv,
                          const float* __restrict__ feat, float* __restrict__ out) {
    int t = blockIdx.x * blockDim.x + threadIdx.x;
    int e = t >> 2;
    int c4 = (t & 3) * 4;
    if (e >= N_EDGES) return;
    int s = src[e], d = dst[e];
    float nrm = dinv[s] * w[e] * dinv[d];
    float4 v = *(const float4*)(feat + (size_t)s * 16 + c4);
    float* o = out + (size_t)d * 16 + c4;
    atomicAdd(o + 0, nrm * v.x);
    atomicAdd(o + 1, nrm * v.y);
    atomicAdd(o + 2, nrm * v.z);
    atomicAdd(o + 3, nrm * v.w);
}

// ===================== launch =====================

extern "C" void kernel_launch(void* const* d_in, const int* in_sizes, int n_in,
                              void* d_out, int out_size, void* d_ws, size_t ws_size,
                              hipStream_t stream) {
    const float* x  = (const float*)d_in[0];
    const int*   ei = (const int*)d_in[1];
    const float* w  = (const float*)d_in[2];
    const float* W1 = (const float*)d_in[3];
    const float* b1 = (const float*)d_in[4];
    const float* W2 = (const float*)d_in[5];
    const float* b2 = (const float*)d_in[6];
    float* out = (float*)d_out;

    const int* src = ei;
    const int* dst = ei + N_EDGES;
    const int B = 256;

    // ---- fast-path workspace layout (16B-aligned blocks) ----
    char* p = (char*)d_ws;
    int*    bucket_cnt = (int*)p;        p += (size_t)((NBUCK + 3) & ~3) * 4;
    int*    spill_cnt  = (int*)p;        p += 16;
    float*  dinv       = (float*)p;      p += (size_t)N_PAD * 4;
    int2*   meta       = (int2*)p;       p += (size_t)N_PAD * 8;
    __half* x16        = (__half*)p;     p += (size_t)N_NODES * 16 * 2;
    __half* h2         = (__half*)p;     p += (size_t)N_NODES * 16 * 2;
    int4*   sp         = (int4*)p;       p += (size_t)SPILL_MAX * 16;
    uint2*  ebuf       = (uint2*)p;      p += (size_t)NBUCK * BCAP * 8;
    const size_t WS_FAST = (size_t)(p - (char*)d_ws);

    if (ws_size >= WS_FAST) {
        k_pre<<<(N_NODES * 16 + B - 1) / B, B, 0, stream>>>(x, x16, bucket_cnt, spill_cnt);
        k_bin<<<BIN_BLOCKS, B, 0, stream>>>(src, dst, w, bucket_cnt, ebuf, sp, spill_cnt);
        k_sort<<<NBUCK, B, 0, stream>>>(ebuf, bucket_cnt, sp, spill_cnt, dinv, meta);
        k_nrm<<<NBUCK, B, 0, stream>>>((uint*)ebuf, bucket_cnt, dinv);
        k_gather_mlp<<<N_NODES / 8, B, 0, stream>>>((const uint*)ebuf, meta,
                                                    sp, spill_cnt, dinv, x16,
                                                    W1, b1, W2, b2, h2, out);
        k_gather2<<<N_NODES / 8, B, 0, stream>>>((const uint*)ebuf, meta,
                                                 sp, spill_cnt, dinv, h2, out);
        return;
    }

    // ---- CSR fallback (round-2 path) ----
    float* deg_dinv = (float*)d_ws;
    int*   cntb     = (int*)(deg_dinv + N_PAD);
    int*   rowptr   = cntb + N_PAD;
    int*   bsum     = rowptr + N_PAD;
    float* agg      = (float*)(bsum + 64);
    int2*  perm     = (int2*)(agg + (size_t)N_NODES * 16);
    const size_t WS_CSR = ((size_t)N_PAD * 3 + 64 + (size_t)N_NODES * 16) * 4
                          + (size_t)N_EDGES * 8;

    if (ws_size >= WS_CSR) {
        k_init<<<(N_NODES + B - 1) / B, B, 0, stream>>>(deg_dinv, cntb);
        k_degcnt<<<(N_EDGES + B - 1) / B, B, 0, stream>>>(dst, w, deg_dinv, cntb);
        k_dinv_agg<<<(N_NODES + B - 1) / B, B, 0, stream>>>(x, deg_dinv, agg);
        k_scan1<<<SCAN_BLOCKS, 256, 0, stream>>>(cntb, rowptr, bsum);
        k_scan2<<<1, 64, 0, stream>>>(bsum);
        k_scan3<<<SCAN_BLOCKS, 256, 0, stream>>>(rowptr, bsum);
        k_fill<<<(N_EDGES + B - 1) / B, B, 0, stream>>>(src, dst, w, deg_dinv,
                                                        rowptr, cntb, perm);
        k_gather<<<N_NODES / 4, B, 0, stream>>>(perm, rowptr, x, agg);
        k_mlp<<<N_NODES / 4, B, 0, stream>>>(agg, W1, b1, W2, b2, deg_dinv, out);
        k_gather<<<N_NODES / 4, B, 0, stream>>>(perm, rowptr, agg, out);
    } else {
        float* deg = (float*)d_ws;
        float* ag  = (float*)d_ws + N_NODES;
        k_init<<<(N_NODES + B - 1) / B, B, 0, stream>>>(deg, (int*)nullptr);
        k_degcnt<<<(N_EDGES + B - 1) / B, B, 0, stream>>>(dst, w, deg, (int*)nullptr);
        k_dinv_agg<<<(N_NODES + B - 1) / B, B, 0, stream>>>(x, deg, ag);
        k_scatter<<<((size_t)N_EDGES * 4 + B - 1) / B, B, 0, stream>>>(src, dst, w, deg, x, ag);
        k_mlp<<<N_NODES / 4, B, 0, stream>>>(ag, W1, b1, W2, b2, deg, out);
        k_scatter<<<((size_t)N_EDGES * 4 + B - 1) / B, B, 0, stream>>>(src, dst, w, deg, ag, out);
    }
}

// Round 12
// 375.934 us; speedup vs baseline: 1.3860x; 1.0410x over previous
//
#include <hip/hip_runtime.h>
#include <hip/hip_fp16.h>

#define N_NODES 100000
#define N_EDGES 3200000
#define N_PAD   100096
#define BNODES  128
#define NBUCK   ((N_NODES + BNODES - 1) / BNODES)       // 782
#define BCAP    4800                                    // mean 4096, sigma 64 (11 sigma)
#define EPB_BIN 8192                                    // edges per bin block (32/thread)
#define BIN_BLOCKS ((N_EDGES + EPB_BIN - 1) / EPB_BIN)  // 391
#define SPILL_MAX 65536
#define WQSCALE  32767.0f
#define NPX      (N_NODES / 8)                          // 12500 nodes per XCD slab
#define SCAN_CHUNK 2048
#define SCAN_BLOCKS ((N_NODES + SCAN_CHUNK - 1) / SCAN_CHUNK)

typedef unsigned int uint;

// ===================== fast path: bin -> sort -> nrm -> gather =====================

// prologue: x -> fp16, zero bucket_cnt/spill_cnt
__global__ __launch_bounds__(256) void k_pre(const float* __restrict__ x,
                                             __half* __restrict__ x16,
                                             int* __restrict__ bucket_cnt,
                                             int* __restrict__ spill_cnt) {
    int i = blockIdx.x * blockDim.x + threadIdx.x;
    if (i < N_NODES * 16) x16[i] = __float2half(x[i]);
    if (i < NBUCK) bucket_cnt[i] = 0;
    if (i == 0) *spill_cnt = 0;
}

// counting-sort edges into 782 dst-buckets; entry = { (dstl<<17)|src , w_bits }
__global__ __launch_bounds__(256) void k_bin(const int* __restrict__ src,
                                             const int* __restrict__ dst,
                                             const float* __restrict__ w,
                                             int* __restrict__ bucket_cnt,
                                             uint2* __restrict__ ebuf,
                                             int4* __restrict__ sp,
                                             int* __restrict__ spill_cnt) {
    __shared__ int hist[NBUCK];
    __shared__ int base[NBUCK];
    __shared__ int rank[NBUCK];
    int tid = threadIdx.x;
    for (int b = tid; b < NBUCK; b += 256) { hist[b] = 0; rank[b] = 0; }
    __syncthreads();
    int e0 = blockIdx.x * EPB_BIN;
#pragma unroll 4
    for (int k = 0; k < 32; k++) {
        int e = e0 + tid + k * 256;
        if (e < N_EDGES) atomicAdd(&hist[__builtin_nontemporal_load(dst + e) >> 7], 1);
    }
    __syncthreads();
    for (int b = tid; b < NBUCK; b += 256) {
        int c = hist[b];
        base[b] = c ? atomicAdd(&bucket_cnt[b], c) : 0;
    }
    __syncthreads();
#pragma unroll 4
    for (int k = 0; k < 32; k++) {
        int e = e0 + tid + k * 256;
        if (e < N_EDGES) {
            int s = __builtin_nontemporal_load(src + e);
            int d = __builtin_nontemporal_load(dst + e);
            float wv = __builtin_nontemporal_load(w + e);
            int b = d >> 7;
            int r = atomicAdd(&rank[b], 1);
            int pos = base[b] + r;
            if (pos < BCAP) {
                ebuf[(size_t)b * BCAP + pos] =
                    make_uint2(((uint)(d & 127) << 17) | (uint)s, __float_as_uint(wv));
            } else {
                int oi = atomicAdd(spill_cnt, 1);
                if (oi < SPILL_MAX) sp[oi] = make_int4(s, d, __float_as_int(wv), 0);
            }
        }
    }
}

// per-bucket: stage in LDS, node-histogram + weighted degree, prefix, scatter to
// node-major 4B entries (overlaying the bucket's own ebuf region); write dinv/meta.
__global__ __launch_bounds__(256) void k_sort(uint2* __restrict__ ebuf,
                                              const int* __restrict__ bucket_cnt,
                                              const int4* __restrict__ sp,
                                              const int* __restrict__ spill_cnt,
                                              float* __restrict__ dinv,
                                              int2* __restrict__ meta) {
    __shared__ uint2 ent[BCAP];          // 38.4 KB
    __shared__ float wacc[BNODES];
    __shared__ int   hist[BNODES];
    __shared__ int   pref[BNODES];
    __shared__ int   curs[BNODES];
    int b = blockIdx.x, tid = threadIdx.x;
    int lo = b * BNODES;
    int n = N_NODES - lo; if (n > BNODES) n = BNODES;
    if (tid < BNODES) { wacc[tid] = 0.0f; hist[tid] = 0; }
    __syncthreads();
    int cnt = bucket_cnt[b]; if (cnt > BCAP) cnt = BCAP;
    const uint2* srcrow = ebuf + (size_t)b * BCAP;
    for (int j = tid; j < cnt; j += 256) {
        uint2 e = srcrow[j];
        ent[j] = e;
        int nl = e.x >> 17;
        atomicAdd(&hist[nl], 1);
        atomicAdd(&wacc[nl], __uint_as_float(e.y));
    }
    int ns = *spill_cnt; if (ns > SPILL_MAX) ns = SPILL_MAX;
    for (int i = tid; i < ns; i += 256) {
        int4 q = sp[i];
        if ((q.y >> 7) == b) atomicAdd(&wacc[q.y & 127], __int_as_float(q.z));
    }
    __syncthreads();
    // inclusive prefix over hist -> pref
    if (tid < BNODES) pref[tid] = hist[tid];
    __syncthreads();
    for (int off = 1; off < BNODES; off <<= 1) {
        int v = 0;
        if (tid < BNODES && tid >= off) v = pref[tid - off];
        __syncthreads();
        if (tid < BNODES) pref[tid] += v;
        __syncthreads();
    }
    if (tid < BNODES) curs[tid] = pref[tid] - hist[tid];   // exclusive start
    if (tid < n) {
        meta[lo + tid] = make_int2(b * (BCAP * 2) + (pref[tid] - hist[tid]), hist[tid]);
        dinv[lo + tid] = rsqrtf(1.0f + wacc[tid]);
    }
    __syncthreads();
    // scatter node-sorted 4B entries over the bucket's own region (source is in LDS)
    uint* outb = (uint*)ebuf + (size_t)b * (BCAP * 2);
    for (int j = tid; j < cnt; j += 256) {
        uint2 e = ent[j];
        int nl = e.x >> 17;
        int pos = atomicAdd(&curs[nl], 1);
        uint wq = __float2uint_rn(__uint_as_float(e.y) * WQSCALE);
        outb[pos] = (wq << 17) | (e.x & 0x1FFFF);
    }
}

// fold dinv[src] into each sorted entry: q15(w) -> q15(dinv[s]*w)
__global__ __launch_bounds__(256) void k_nrm(uint* __restrict__ sbuf,
                                             const int* __restrict__ bucket_cnt,
                                             const float* __restrict__ dinv) {
    int b = blockIdx.x, tid = threadIdx.x;
    int cnt = bucket_cnt[b]; if (cnt > BCAP) cnt = BCAP;
    uint* outb = sbuf + (size_t)b * (BCAP * 2);
    for (int j = tid; j < cnt; j += 256) {
        uint e = outb[j];
        int s = e & 0x1FFFF;
        float wv = (float)(e >> 17) * (1.0f / WQSCALE);
        uint q = __float2uint_rn(dinv[s] * wv * WQSCALE);
        outb[j] = (q << 17) | (uint)s;
    }
}

// fused: layer-1 gather (single-shot: 2 edges/lane covers 64 edges) + self + MLP.
// One node per wave; 4 nodes/block; XCD slab swizzle; no nontemporal hints.
__global__ __launch_bounds__(256) void k_gather_mlp(const uint* __restrict__ sbuf,
                                                    const int2* __restrict__ meta,
                                                    const int4* __restrict__ sp,
                                                    const int* __restrict__ spill_cnt,
                                                    const float* __restrict__ dinv,
                                                    const __half* __restrict__ x16,
                                                    const float* __restrict__ W1,
                                                    const float* __restrict__ b1,
                                                    const float* __restrict__ W2,
                                                    const float* __restrict__ b2,
                                                    __half* __restrict__ h2,
                                                    float* __restrict__ out) {
    __shared__ float fvs[4][16];
    __shared__ float o1s[4][128];
    int wave = threadIdx.x >> 6, lane = threadIdx.x & 63;
    int node = (blockIdx.x & 7) * NPX + (blockIdx.x >> 3) * 4 + wave;   // XCD slab
    int c2 = lane & 1, eo = lane >> 1;
    int2 mm = meta[node];
    int beg = mm.x, cnt = mm.y;
    float di = dinv[node];
    const uint* row = sbuf + beg;
    // single shot: edges 2*eo and 2*eo+1 (covers 64 >= cnt for ~all nodes)
    int j0 = 2 * eo, j1 = 2 * eo + 1;
    uint e0 = row[(j0 < cnt) ? j0 : 0];
    uint e1 = row[(j1 < cnt) ? j1 : 0];
    float nq0 = (j0 < cnt) ? (float)(e0 >> 17) * (1.0f / WQSCALE) : 0.0f;
    float nq1 = (j1 < cnt) ? (float)(e1 >> 17) * (1.0f / WQSCALE) : 0.0f;
    int s0 = e0 & 0x1FFFF, s1 = e1 & 0x1FFFF;
    uint4 hv0 = *(const uint4*)(x16 + (size_t)s0 * 16 + c2 * 8);
    uint4 hv1 = *(const uint4*)(x16 + (size_t)s1 * 16 + c2 * 8);
    float acc[8];
    {
        float2 a0 = __half22float2(*(__half2*)&hv0.x);
        float2 a1 = __half22float2(*(__half2*)&hv0.y);
        float2 a2 = __half22float2(*(__half2*)&hv0.z);
        float2 a3 = __half22float2(*(__half2*)&hv0.w);
        float2 b0 = __half22float2(*(__half2*)&hv1.x);
        float2 b1v = __half22float2(*(__half2*)&hv1.y);
        float2 b2v = __half22float2(*(__half2*)&hv1.z);
        float2 b3 = __half22float2(*(__half2*)&hv1.w);
        acc[0] = nq0 * a0.x + nq1 * b0.x;  acc[1] = nq0 * a0.y + nq1 * b0.y;
        acc[2] = nq0 * a1.x + nq1 * b1v.x; acc[3] = nq0 * a1.y + nq1 * b1v.y;
        acc[4] = nq0 * a2.x + nq1 * b2v.x; acc[5] = nq0 * a2.y + nq1 * b2v.y;
        acc[6] = nq0 * a3.x + nq1 * b3.x;  acc[7] = nq0 * a3.y + nq1 * b3.y;
    }
    // rare tail: cnt > 64
    for (int j = 64 + 2 * eo; j < cnt; j += 64) {
        uint ea = row[j];
        uint eb = row[((j + 1) < cnt) ? (j + 1) : 0];
        float na = (float)(ea >> 17) * (1.0f / WQSCALE);
        float nb = ((j + 1) < cnt) ? (float)(eb >> 17) * (1.0f / WQSCALE) : 0.0f;
        int sa = ea & 0x1FFFF, sb = eb & 0x1FFFF;
        uint4 ha = *(const uint4*)(x16 + (size_t)sa * 16 + c2 * 8);
        uint4 hb = *(const uint4*)(x16 + (size_t)sb * 16 + c2 * 8);
        float2 a0 = __half22float2(*(__half2*)&ha.x);
        float2 a1 = __half22float2(*(__half2*)&ha.y);
        float2 a2 = __half22float2(*(__half2*)&ha.z);
        float2 a3 = __half22float2(*(__half2*)&ha.w);
        float2 b0 = __half22float2(*(__half2*)&hb.x);
        float2 b1v = __half22float2(*(__half2*)&hb.y);
        float2 b2v = __half22float2(*(__half2*)&hb.z);
        float2 b3 = __half22float2(*(__half2*)&hb.w);
        acc[0] += na * a0.x + nb * b0.x;  acc[1] += na * a0.y + nb * b0.y;
        acc[2] += na * a1.x + nb * b1v.x; acc[3] += na * a1.y + nb * b1v.y;
        acc[4] += na * a2.x + nb * b2v.x; acc[5] += na * a2.y + nb * b2v.y;
        acc[6] += na * a3.x + nb * b3.x;  acc[7] += na * a3.y + nb * b3.y;
    }
#pragma unroll
    for (int m = 2; m < 64; m <<= 1) {
#pragma unroll
        for (int k = 0; k < 8; k++) acc[k] += __shfl_xor(acc[k], m, 64);
    }
    if (lane < 2) {
        uint4 hv = *(const uint4*)(x16 + (size_t)node * 16 + c2 * 8);
        float2 s0f = __half22float2(*(__half2*)&hv.x);
        float2 s1f = __half22float2(*(__half2*)&hv.y);
        float2 s2f = __half22float2(*(__half2*)&hv.z);
        float2 s3f = __half22float2(*(__half2*)&hv.w);
        float slf[8] = {s0f.x, s0f.y, s1f.x, s1f.y, s2f.x, s2f.y, s3f.x, s3f.y};
        float r[8];
#pragma unroll
        for (int k = 0; k < 8; k++) r[k] = acc[k] + di * slf[k];
        int ns = *spill_cnt;                       // 0 in practice
        if (ns > 0) {
            if (ns > SPILL_MAX) ns = SPILL_MAX;
            for (int i = 0; i < ns; i++) {
                int4 q = sp[i];
                if (q.y == node) {
                    float f = dinv[q.x] * __int_as_float(q.z);
                    uint4 qv = *(const uint4*)(x16 + (size_t)q.x * 16 + c2 * 8);
                    float2 u0 = __half22float2(*(__half2*)&qv.x);
                    float2 u1 = __half22float2(*(__half2*)&qv.y);
                    float2 u2 = __half22float2(*(__half2*)&qv.z);
                    float2 u3 = __half22float2(*(__half2*)&qv.w);
                    float uv[8] = {u0.x, u0.y, u1.x, u1.y, u2.x, u2.y, u3.x, u3.y};
                    for (int k = 0; k < 8; k++) r[k] += f * uv[k];
                }
            }
        }
#pragma unroll
        for (int k = 0; k < 8; k++) fvs[wave][c2 * 8 + k] = r[k] * di;
    }
    __syncthreads();
    float fv[16];
#pragma unroll
    for (int k = 0; k < 16; k++) fv[k] = fvs[wave][k];
    float a = b1[2 * lane], bb = b1[2 * lane + 1];
#pragma unroll
    for (int k = 0; k < 16; k++) {
        float2 wv = *(const float2*)(W1 + k * 128 + 2 * lane);
        a = fmaf(fv[k], wv.x, a);
        bb = fmaf(fv[k], wv.y, bb);
    }
    o1s[wave][2 * lane + 0] = fmaxf(a, 0.0f);
    o1s[wave][2 * lane + 1] = fmaxf(bb, 0.0f);
    __syncthreads();
    int c = lane & 15, g = lane >> 4;
    float p = 0.0f;
#pragma unroll
    for (int k = 0; k < 32; k++) {
        int kk = g * 32 + k;
        p = fmaf(o1s[wave][kk], W2[kk * 16 + c], p);
    }
    p += __shfl_down(p, 16, 64);
    p += __shfl_down(p, 32, 64);
    if (lane < 16) {
        h2[(size_t)node * 16 + c] = __float2half(p);
        out[(size_t)node * 16 + c] = di * di * p + b2[c];
    }
}

// layer-2 gather: out[node] += di * (sum q*h2[s] + spill); single-shot form.
__global__ __launch_bounds__(256) void k_gather2(const uint* __restrict__ sbuf,
                                                 const int2* __restrict__ meta,
                                                 const int4* __restrict__ sp,
                                                 const int* __restrict__ spill_cnt,
                                                 const float* __restrict__ dinv,
                                                 const __half* __restrict__ h2,
                                                 float* __restrict__ out) {
    int wave = threadIdx.x >> 6, lane = threadIdx.x & 63;
    int node = (blockIdx.x & 7) * NPX + (blockIdx.x >> 3) * 4 + wave;
    int c2 = lane & 1, eo = lane >> 1;
    int2 mm = meta[node];
    int beg = mm.x, cnt = mm.y;
    float di = dinv[node];
    const uint* row = sbuf + beg;
    int j0 = 2 * eo, j1 = 2 * eo + 1;
    uint e0 = row[(j0 < cnt) ? j0 : 0];
    uint e1 = row[(j1 < cnt) ? j1 : 0];
    float nq0 = (j0 < cnt) ? (float)(e0 >> 17) * (1.0f / WQSCALE) : 0.0f;
    float nq1 = (j1 < cnt) ? (float)(e1 >> 17) * (1.0f / WQSCALE) : 0.0f;
    int s0 = e0 & 0x1FFFF, s1 = e1 & 0x1FFFF;
    uint4 hv0 = *(const uint4*)(h2 + (size_t)s0 * 16 + c2 * 8);
    uint4 hv1 = *(const uint4*)(h2 + (size_t)s1 * 16 + c2 * 8);
    float acc[8];
    {
        float2 a0 = __half22float2(*(__half2*)&hv0.x);
        float2 a1 = __half22float2(*(__half2*)&hv0.y);
        float2 a2 = __half22float2(*(__half2*)&hv0.z);
        float2 a3 = __half22float2(*(__half2*)&hv0.w);
        float2 b0 = __half22float2(*(__half2*)&hv1.x);
        float2 b1v = __half22float2(*(__half2*)&hv1.y);
        float2 b2v = __half22float2(*(__half2*)&hv1.z);
        float2 b3 = __half22float2(*(__half2*)&hv1.w);
        acc[0] = nq0 * a0.x + nq1 * b0.x;  acc[1] = nq0 * a0.y + nq1 * b0.y;
        acc[2] = nq0 * a1.x + nq1 * b1v.x; acc[3] = nq0 * a1.y + nq1 * b1v.y;
        acc[4] = nq0 * a2.x + nq1 * b2v.x; acc[5] = nq0 * a2.y + nq1 * b2v.y;
        acc[6] = nq0 * a3.x + nq1 * b3.x;  acc[7] = nq0 * a3.y + nq1 * b3.y;
    }
    for (int j = 64 + 2 * eo; j < cnt; j += 64) {
        uint ea = row[j];
        uint eb = row[((j + 1) < cnt) ? (j + 1) : 0];
        float na = (float)(ea >> 17) * (1.0f / WQSCALE);
        float nb = ((j + 1) < cnt) ? (float)(eb >> 17) * (1.0f / WQSCALE) : 0.0f;
        int sa = ea & 0x1FFFF, sb = eb & 0x1FFFF;
        uint4 ha = *(const uint4*)(h2 + (size_t)sa * 16 + c2 * 8);
        uint4 hb = *(const uint4*)(h2 + (size_t)sb * 16 + c2 * 8);
        float2 a0 = __half22float2(*(__half2*)&ha.x);
        float2 a1 = __half22float2(*(__half2*)&ha.y);
        float2 a2 = __half22float2(*(__half2*)&ha.z);
        float2 a3 = __half22float2(*(__half2*)&ha.w);
        float2 b0 = __half22float2(*(__half2*)&hb.x);
        float2 b1v = __half22float2(*(__half2*)&hb.y);
        float2 b2v = __half22float2(*(__half2*)&hb.z);
        float2 b3 = __half22float2(*(__half2*)&hb.w);
        acc[0] += na * a0.x + nb * b0.x;  acc[1] += na * a0.y + nb * b0.y;
        acc[2] += na * a1.x + nb * b1v.x; acc[3] += na * a1.y + nb * b1v.y;
        acc[4] += na * a2.x + nb * b2v.x; acc[5] += na * a2.y + nb * b2v.y;
        acc[6] += na * a3.x + nb * b3.x;  acc[7] += na * a3.y + nb * b3.y;
    }
#pragma unroll
    for (int m = 2; m < 64; m <<= 1) {
#pragma unroll
        for (int k = 0; k < 8; k++) acc[k] += __shfl_xor(acc[k], m, 64);
    }
    if (lane < 2) {
        int ns = *spill_cnt;
        if (ns > 0) {
            if (ns > SPILL_MAX) ns = SPILL_MAX;
            for (int i = 0; i < ns; i++) {
                int4 q = sp[i];
                if (q.y == node) {
                    float f = dinv[q.x] * __int_as_float(q.z);
                    uint4 qv = *(const uint4*)(h2 + (size_t)q.x * 16 + c2 * 8);
                    float2 u0 = __half22float2(*(__half2*)&qv.x);
                    float2 u1 = __half22float2(*(__half2*)&qv.y);
                    float2 u2 = __half22float2(*(__half2*)&qv.z);
                    float2 u3 = __half22float2(*(__half2*)&qv.w);
                    float uv[8] = {u0.x, u0.y, u1.x, u1.y, u2.x, u2.y, u3.x, u3.y};
                    for (int k = 0; k < 8; k++) acc[k] += f * uv[k];
                }
            }
        }
        float4* op = (float4*)(out + (size_t)node * 16 + c2 * 8);
        float4 o0 = op[0], o1 = op[1];
        o0.x += di * acc[0]; o0.y += di * acc[1];
        o0.z += di * acc[2]; o0.w += di * acc[3];
        o1.x += di * acc[4]; o1.y += di * acc[5];
        o1.z += di * acc[6]; o1.w += di * acc[7];
        op[0] = o0; op[1] = o1;
    }
}

// ===================== CSR fallback (round-2) =====================

__global__ void k_init(float* __restrict__ deg, int* __restrict__ cnt) {
    int i = blockIdx.x * blockDim.x + threadIdx.x;
    if (i < N_NODES) { deg[i] = 1.0f; if (cnt) cnt[i] = 0; }
}

__global__ void k_degcnt(const int* __restrict__ dst, const float* __restrict__ w,
                         float* __restrict__ deg, int* __restrict__ cnt) {
    int e = blockIdx.x * blockDim.x + threadIdx.x;
    if (e < N_EDGES) {
        int d = dst[e];
        atomicAdd(&deg[d], w[e]);
        if (cnt) atomicAdd(&cnt[d], 1);
    }
}

__global__ void k_dinv_agg(const float* __restrict__ x, float* __restrict__ deg_dinv,
                           float* __restrict__ agg) {
    int i = blockIdx.x * blockDim.x + threadIdx.x;
    if (i >= N_NODES) return;
    float di = rsqrtf(deg_dinv[i]);
    deg_dinv[i] = di;
    float s = di * di;
    const float4* xr = (const float4*)(x + (size_t)i * 16);
    float4* ar = (float4*)(agg + (size_t)i * 16);
#pragma unroll
    for (int k = 0; k < 4; k++) {
        float4 v = xr[k];
        v.x *= s; v.y *= s; v.z *= s; v.w *= s;
        ar[k] = v;
    }
}

__global__ __launch_bounds__(256) void k_scan1(const int* __restrict__ cnt,
                                               int* __restrict__ rowptr,
                                               int* __restrict__ bsum) {
    __shared__ int ts[256];
    int tid = threadIdx.x;
    int base = blockIdx.x * SCAN_CHUNK + tid * 8;
    int v[8]; int s = 0;
#pragma unroll
    for (int k = 0; k < 8; k++) {
        int idx = base + k;
        v[k] = (idx < N_NODES) ? cnt[idx] : 0;
        s += v[k];
    }
    ts[tid] = s;
    __syncthreads();
    for (int off = 1; off < 256; off <<= 1) {
        int t = (tid >= off) ? ts[tid - off] : 0;
        __syncthreads();
        ts[tid] += t;
        __syncthreads();
    }
    int run = ts[tid] - s;
#pragma unroll
    for (int k = 0; k < 8; k++) {
        int idx = base + k;
        if (idx < N_NODES) rowptr[idx] = run;
        run += v[k];
    }
    if (tid == 255) bsum[blockIdx.x] = ts[255];
}

__global__ void k_scan2(int* __restrict__ bsum) {
    if (threadIdx.x == 0 && blockIdx.x == 0) {
        int run = 0;
        for (int g = 0; g < SCAN_BLOCKS; g++) { int t = bsum[g]; bsum[g] = run; run += t; }
    }
}

__global__ __launch_bounds__(256) void k_scan3(int* __restrict__ rowptr,
                                               const int* __restrict__ bsum) {
    int tid = threadIdx.x;
    int base = blockIdx.x * SCAN_CHUNK + tid * 8;
    int off = bsum[blockIdx.x];
#pragma unroll
    for (int k = 0; k < 8; k++) {
        int idx = base + k;
        if (idx < N_NODES) rowptr[idx] += off;
    }
    if (blockIdx.x == 0 && tid == 0) rowptr[N_NODES] = N_EDGES;
}

__global__ void k_fill(const int* __restrict__ src, const int* __restrict__ dst,
                       const float* __restrict__ w, const float* __restrict__ dinv,
                       const int* __restrict__ rowptr, int* __restrict__ cnt,
                       int2* __restrict__ perm) {
    int e = blockIdx.x * blockDim.x + threadIdx.x;
    if (e >= N_EDGES) return;
    int s = src[e], d = dst[e];
    float nrm = dinv[s] * w[e] * dinv[d];
    int r = atomicSub(&cnt[d], 1) - 1;
    int pos = rowptr[d] + r;
    perm[pos] = make_int2(s, __float_as_int(nrm));
}

__global__ __launch_bounds__(256) void k_gather(const int2* __restrict__ perm,
                                                const int* __restrict__ rowptr,
                                                const float* __restrict__ feat,
                                                float* __restrict__ out) {
    int wave = threadIdx.x >> 6, lane = threadIdx.x & 63;
    int node = blockIdx.x * 4 + wave;
    int c = lane & 15, eo = lane >> 4;
    int beg = rowptr[node], end = rowptr[node + 1];
    float acc = 0.0f;
    for (int j = beg + eo; j < end; j += 4) {
        int2 ed = perm[j];
        acc = fmaf(__int_as_float(ed.y), feat[(size_t)ed.x * 16 + c], acc);
    }
    acc += __shfl_xor(acc, 16, 64);
    acc += __shfl_xor(acc, 32, 64);
    if (lane < 16) out[(size_t)node * 16 + c] += acc;
}

__global__ __launch_bounds__(256) void k_mlp(float* __restrict__ agg,
                                             const float* __restrict__ W1,
                                             const float* __restrict__ b1,
                                             const float* __restrict__ W2,
                                             const float* __restrict__ b2,
                                             const float* __restrict__ dinv,
                                             float* __restrict__ out) {
    __shared__ float o1s[4][128];
    int wave = threadIdx.x >> 6;
    int lane = threadIdx.x & 63;
    int node = blockIdx.x * 4 + wave;
    const float* f = agg + (size_t)node * 16;
    float fv[16];
#pragma unroll
    for (int k = 0; k < 4; k++) {
        float4 v = ((const float4*)f)[k];
        fv[4 * k + 0] = v.x; fv[4 * k + 1] = v.y; fv[4 * k + 2] = v.z; fv[4 * k + 3] = v.w;
    }
    float a = b1[2 * lane], b = b1[2 * lane + 1];
#pragma unroll
    for (int k = 0; k < 16; k++) {
        float2 wv = *(const float2*)(W1 + k * 128 + 2 * lane);
        a = fmaf(fv[k], wv.x, a);
        b = fmaf(fv[k], wv.y, b);
    }
    o1s[wave][2 * lane + 0] = fmaxf(a, 0.0f);
    o1s[wave][2 * lane + 1] = fmaxf(b, 0.0f);
    __syncthreads();
    int c = lane & 15, g = lane >> 4;
    float p = 0.0f;
#pragma unroll
    for (int k = 0; k < 32; k++) {
        int kk = g * 32 + k;
        p = fmaf(o1s[wave][kk], W2[kk * 16 + c], p);
    }
    p += __shfl_down(p, 16, 64);
    p += __shfl_down(p, 32, 64);
    __syncthreads();
    if (lane < 16) {
        float h2v = p;
        agg[(size_t)node * 16 + c] = h2v;
        float di = dinv[node];
        out[(size_t)node * 16 + c] = di * di * h2v + b2[c];
    }
}

__global__ void k_scatter(const int* __restrict__ src, const int* __restrict__ dst,
                          const float* __restrict__ w, const float* __restrict__ dinv,
                          const float* __restrict__ feat, float* __restrict__ out) {
    int t = blockIdx.x * blockDim.x + threadIdx.x;
    int e = t >> 2;
    int c4 = (t & 3) * 4;
    if (e >= N_EDGES) return;
    int s = src[e], d = dst[e];
    float nrm = dinv[s] * w[e] * dinv[d];
    float4 v = *(const float4*)(feat + (size_t)s * 16 + c4);
    float* o = out + (size_t)d * 16 + c4;
    atomicAdd(o + 0, nrm * v.x);
    atomicAdd(o + 1, nrm * v.y);
    atomicAdd(o + 2, nrm * v.z);
    atomicAdd(o + 3, nrm * v.w);
}

// ===================== launch =====================

extern "C" void kernel_launch(void* const* d_in, const int* in_sizes, int n_in,
                              void* d_out, int out_size, void* d_ws, size_t ws_size,
                              hipStream_t stream) {
    const float* x  = (const float*)d_in[0];
    const int*   ei = (const int*)d_in[1];
    const float* w  = (const float*)d_in[2];
    const float* W1 = (const float*)d_in[3];
    const float* b1 = (const float*)d_in[4];
    const float* W2 = (const float*)d_in[5];
    const float* b2 = (const float*)d_in[6];
    float* out = (float*)d_out;

    const int* src = ei;
    const int* dst = ei + N_EDGES;
    const int B = 256;

    // ---- fast-path workspace layout (16B-aligned blocks) ----
    char* p = (char*)d_ws;
    int*    bucket_cnt = (int*)p;        p += (size_t)((NBUCK + 3) & ~3) * 4;
    int*    spill_cnt  = (int*)p;        p += 16;
    float*  dinv       = (float*)p;      p += (size_t)N_PAD * 4;
    int2*   meta       = (int2*)p;       p += (size_t)N_PAD * 8;
    __half* x16        = (__half*)p;     p += (size_t)N_NODES * 16 * 2;
    __half* h2         = (__half*)p;     p += (size_t)N_NODES * 16 * 2;
    int4*   sp         = (int4*)p;       p += (size_t)SPILL_MAX * 16;
    uint2*  ebuf       = (uint2*)p;      p += (size_t)NBUCK * BCAP * 8;
    const size_t WS_FAST = (size_t)(p - (char*)d_ws);

    if (ws_size >= WS_FAST) {
        k_pre<<<(N_NODES * 16 + B - 1) / B, B, 0, stream>>>(x, x16, bucket_cnt, spill_cnt);
        k_bin<<<BIN_BLOCKS, B, 0, stream>>>(src, dst, w, bucket_cnt, ebuf, sp, spill_cnt);
        k_sort<<<NBUCK, B, 0, stream>>>(ebuf, bucket_cnt, sp, spill_cnt, dinv, meta);
        k_nrm<<<NBUCK, B, 0, stream>>>((uint*)ebuf, bucket_cnt, dinv);
        k_gather_mlp<<<N_NODES / 4, B, 0, stream>>>((const uint*)ebuf, meta,
                                                    sp, spill_cnt, dinv, x16,
                                                    W1, b1, W2, b2, h2, out);
        k_gather2<<<N_NODES / 4, B, 0, stream>>>((const uint*)ebuf, meta,
                                                 sp, spill_cnt, dinv, h2, out);
        return;
    }

    // ---- CSR fallback (round-2 path) ----
    float* deg_dinv = (float*)d_ws;
    int*   cntb     = (int*)(deg_dinv + N_PAD);
    int*   rowptr   = cntb + N_PAD;
    int*   bsum     = rowptr + N_PAD;
    float* agg      = (float*)(bsum + 64);
    int2*  perm     = (int2*)(agg + (size_t)N_NODES * 16);
    const size_t WS_CSR = ((size_t)N_PAD * 3 + 64 + (size_t)N_NODES * 16) * 4
                          + (size_t)N_EDGES * 8;

    if (ws_size >= WS_CSR) {
        k_init<<<(N_NODES + B - 1) / B, B, 0, stream>>>(deg_dinv, cntb);
        k_degcnt<<<(N_EDGES + B - 1) / B, B, 0, stream>>>(dst, w, deg_dinv, cntb);
        k_dinv_agg<<<(N_NODES + B - 1) / B, B, 0, stream>>>(x, deg_dinv, agg);
        k_scan1<<<SCAN_BLOCKS, 256, 0, stream>>>(cntb, rowptr, bsum);
        k_scan2<<<1, 64, 0, stream>>>(bsum);
        k_scan3<<<SCAN_BLOCKS, 256, 0, stream>>>(rowptr, bsum);
        k_fill<<<(N_EDGES + B - 1) / B, B, 0, stream>>>(src, dst, w, deg_dinv,
                                                        rowptr, cntb, perm);
        k_gather<<<N_NODES / 4, B, 0, stream>>>(perm, rowptr, x, agg);
        k_mlp<<<N_NODES / 4, B, 0, stream>>>(agg, W1, b1, W2, b2, deg_dinv, out);
        k_gather<<<N_NODES / 4, B, 0, stream>>>(perm, rowptr, agg, out);
    } else {
        float* deg = (float*)d_ws;
        float* ag  = (float*)d_ws + N_NODES;
        k_init<<<(N_NODES + B - 1) / B, B, 0, stream>>>(deg, (int*)nullptr);
        k_degcnt<<<(N_EDGES + B - 1) / B, B, 0, stream>>>(dst, w, deg, (int*)nullptr);
        k_dinv_agg<<<(N_NODES + B - 1) / B, B, 0, stream>>>(x, deg, ag);
        k_scatter<<<((size_t)N_EDGES * 4 + B - 1) / B, B, 0, stream>>>(src, dst, w, deg, x, ag);
        k_mlp<<<N_NODES / 4, B, 0, stream>>>(ag, W1, b1, W2, b2, deg, out);
        k_scatter<<<((size_t)N_EDGES * 4 + B - 1) / B, B, 0, stream>>>(src, dst, w, deg, ag, out);
    }
}

// Round 13
// 362.543 us; speedup vs baseline: 1.4372x; 1.0369x over previous
//
#include <hip/hip_runtime.h>
#include <hip/hip_fp16.h>

#define N_NODES 100000
#define N_EDGES 3200000
#define N_PAD   100096
#define BNODES  128
#define NBUCK   ((N_NODES + BNODES - 1) / BNODES)       // 782
#define BCAP    4800                                    // mean 4096, sigma 64 (11 sigma)
#define EPB_BIN 8192                                    // edges per bin block (32/thread)
#define BIN_BLOCKS ((N_EDGES + EPB_BIN - 1) / EPB_BIN)  // 391
#define SPILL_MAX 65536
#define WQSCALE  32767.0f
#define NPX      (N_NODES / 8)                          // 12500 nodes per XCD slab
#define SCAN_CHUNK 2048
#define SCAN_BLOCKS ((N_NODES + SCAN_CHUNK - 1) / SCAN_CHUNK)

typedef unsigned int uint;
typedef unsigned short ushort;

__device__ __forceinline__ __half2 as_h2(uint u) { return *reinterpret_cast<__half2*>(&u); }
__device__ __forceinline__ uint as_u32(__half2 h) { return *reinterpret_cast<uint*>(&h); }

// ===================== fast path: bin -> sort -> nrm -> gather =====================

// prologue: x -> fp16, zero bucket_cnt/spill_cnt
__global__ __launch_bounds__(256) void k_pre(const float* __restrict__ x,
                                             __half* __restrict__ x16,
                                             int* __restrict__ bucket_cnt,
                                             int* __restrict__ spill_cnt) {
    int i = blockIdx.x * blockDim.x + threadIdx.x;
    if (i < N_NODES * 16) x16[i] = __float2half(x[i]);
    if (i < NBUCK) bucket_cnt[i] = 0;
    if (i == 0) *spill_cnt = 0;
}

// counting-sort edges into 782 dst-buckets; entry = { (dstl<<17)|src , w_bits }
__global__ __launch_bounds__(256) void k_bin(const int* __restrict__ src,
                                             const int* __restrict__ dst,
                                             const float* __restrict__ w,
                                             int* __restrict__ bucket_cnt,
                                             uint2* __restrict__ ebuf,
                                             int4* __restrict__ sp,
                                             int* __restrict__ spill_cnt) {
    __shared__ int hist[NBUCK];
    __shared__ int base[NBUCK];
    __shared__ int rank[NBUCK];
    int tid = threadIdx.x;
    for (int b = tid; b < NBUCK; b += 256) { hist[b] = 0; rank[b] = 0; }
    __syncthreads();
    int e0 = blockIdx.x * EPB_BIN;
#pragma unroll 4
    for (int k = 0; k < 32; k++) {
        int e = e0 + tid + k * 256;
        if (e < N_EDGES) atomicAdd(&hist[__builtin_nontemporal_load(dst + e) >> 7], 1);
    }
    __syncthreads();
    for (int b = tid; b < NBUCK; b += 256) {
        int c = hist[b];
        base[b] = c ? atomicAdd(&bucket_cnt[b], c) : 0;
    }
    __syncthreads();
#pragma unroll 4
    for (int k = 0; k < 32; k++) {
        int e = e0 + tid + k * 256;
        if (e < N_EDGES) {
            int s = __builtin_nontemporal_load(src + e);
            int d = __builtin_nontemporal_load(dst + e);
            float wv = __builtin_nontemporal_load(w + e);
            int b = d >> 7;
            int r = atomicAdd(&rank[b], 1);
            int pos = base[b] + r;
            if (pos < BCAP) {
                ebuf[(size_t)b * BCAP + pos] =
                    make_uint2(((uint)(d & 127) << 17) | (uint)s, __float_as_uint(wv));
            } else {
                int oi = atomicAdd(spill_cnt, 1);
                if (oi < SPILL_MAX) sp[oi] = make_int4(s, d, __float_as_int(wv), 0);
            }
        }
    }
}

// per-bucket: stage in LDS, node-histogram + weighted degree, prefix, scatter to
// node-major 4B entries (overlaying the bucket's own ebuf region); write dinv/meta.
__global__ __launch_bounds__(256) void k_sort(uint2* __restrict__ ebuf,
                                              const int* __restrict__ bucket_cnt,
                                              const int4* __restrict__ sp,
                                              const int* __restrict__ spill_cnt,
                                              float* __restrict__ dinv,
                                              int2* __restrict__ meta) {
    __shared__ uint2 ent[BCAP];          // 38.4 KB
    __shared__ float wacc[BNODES];
    __shared__ int   hist[BNODES];
    __shared__ int   pref[BNODES];
    __shared__ int   curs[BNODES];
    int b = blockIdx.x, tid = threadIdx.x;
    int lo = b * BNODES;
    int n = N_NODES - lo; if (n > BNODES) n = BNODES;
    if (tid < BNODES) { wacc[tid] = 0.0f; hist[tid] = 0; }
    __syncthreads();
    int cnt = bucket_cnt[b]; if (cnt > BCAP) cnt = BCAP;
    const uint2* srcrow = ebuf + (size_t)b * BCAP;
    for (int j = tid; j < cnt; j += 256) {
        uint2 e = srcrow[j];
        ent[j] = e;
        int nl = e.x >> 17;
        atomicAdd(&hist[nl], 1);
        atomicAdd(&wacc[nl], __uint_as_float(e.y));
    }
    int ns = *spill_cnt; if (ns > SPILL_MAX) ns = SPILL_MAX;
    for (int i = tid; i < ns; i += 256) {
        int4 q = sp[i];
        if ((q.y >> 7) == b) atomicAdd(&wacc[q.y & 127], __int_as_float(q.z));
    }
    __syncthreads();
    // inclusive prefix over hist -> pref
    if (tid < BNODES) pref[tid] = hist[tid];
    __syncthreads();
    for (int off = 1; off < BNODES; off <<= 1) {
        int v = 0;
        if (tid < BNODES && tid >= off) v = pref[tid - off];
        __syncthreads();
        if (tid < BNODES) pref[tid] += v;
        __syncthreads();
    }
    if (tid < BNODES) curs[tid] = pref[tid] - hist[tid];   // exclusive start
    if (tid < n) {
        meta[lo + tid] = make_int2(b * (BCAP * 2) + (pref[tid] - hist[tid]), hist[tid]);
        dinv[lo + tid] = rsqrtf(1.0f + wacc[tid]);
    }
    __syncthreads();
    // scatter node-sorted 4B entries over the bucket's own region (source is in LDS)
    uint* outb = (uint*)ebuf + (size_t)b * (BCAP * 2);
    for (int j = tid; j < cnt; j += 256) {
        uint2 e = ent[j];
        int nl = e.x >> 17;
        int pos = atomicAdd(&curs[nl], 1);
        uint wq = __float2uint_rn(__uint_as_float(e.y) * WQSCALE);
        outb[pos] = (wq << 17) | (e.x & 0x1FFFF);
    }
}

// fold dinv[src] into each sorted entry: q15(w) -> fp16-bits(dinv[s]*w)
// (positive fp16 < 1 has sign=0 -> the 16-bit pattern fits in 15 bits)
__global__ __launch_bounds__(256) void k_nrm(uint* __restrict__ sbuf,
                                             const int* __restrict__ bucket_cnt,
                                             const float* __restrict__ dinv) {
    int b = blockIdx.x, tid = threadIdx.x;
    int cnt = bucket_cnt[b]; if (cnt > BCAP) cnt = BCAP;
    uint* outb = sbuf + (size_t)b * (BCAP * 2);
    for (int j = tid; j < cnt; j += 256) {
        uint e = outb[j];
        int s = e & 0x1FFFF;
        float wv = (float)(e >> 17) * (1.0f / WQSCALE);
        __half h = __float2half(dinv[s] * wv);
        uint q = (uint)__half_as_ushort(h);           // <= 0x3C00, fits 15 bits
        outb[j] = (q << 17) | (uint)s;
    }
}

// fused: layer-1 gather (packed fp16 math, single-shot 2 edges/lane) + self + MLP.
__global__ __launch_bounds__(256) void k_gather_mlp(const uint* __restrict__ sbuf,
                                                    const int2* __restrict__ meta,
                                                    const int4* __restrict__ sp,
                                                    const int* __restrict__ spill_cnt,
                                                    const float* __restrict__ dinv,
                                                    const __half* __restrict__ x16,
                                                    const float* __restrict__ W1,
                                                    const float* __restrict__ b1,
                                                    const float* __restrict__ W2,
                                                    const float* __restrict__ b2,
                                                    __half* __restrict__ h2,
                                                    float* __restrict__ out) {
    __shared__ float fvs[4][16];
    __shared__ float o1s[4][128];
    int wave = threadIdx.x >> 6, lane = threadIdx.x & 63;
    int node = (blockIdx.x & 7) * NPX + (blockIdx.x >> 3) * 4 + wave;   // XCD slab
    int c2 = lane & 1, eo = lane >> 1;
    int2 mm = meta[node];
    int beg = mm.x, cnt = mm.y;
    float di = dinv[node];
    const uint* row = sbuf + beg;
    int j0 = 2 * eo, j1 = 2 * eo + 1;
    uint e0 = row[(j0 < cnt) ? j0 : 0];
    uint e1 = row[(j1 < cnt) ? j1 : 0];
    ushort qb0 = (j0 < cnt) ? (ushort)(e0 >> 17) : (ushort)0;
    ushort qb1 = (j1 < cnt) ? (ushort)(e1 >> 17) : (ushort)0;
    __half2 nq0 = __half2half2(__ushort_as_half(qb0));
    __half2 nq1 = __half2half2(__ushort_as_half(qb1));
    int s0 = e0 & 0x1FFFF, s1 = e1 & 0x1FFFF;
    uint4 hv0 = *(const uint4*)(x16 + (size_t)s0 * 16 + c2 * 8);
    uint4 hv1 = *(const uint4*)(x16 + (size_t)s1 * 16 + c2 * 8);
    __half2 acc[4];
    acc[0] = __hfma2(nq1, as_h2(hv1.x), __hmul2(nq0, as_h2(hv0.x)));
    acc[1] = __hfma2(nq1, as_h2(hv1.y), __hmul2(nq0, as_h2(hv0.y)));
    acc[2] = __hfma2(nq1, as_h2(hv1.z), __hmul2(nq0, as_h2(hv0.z)));
    acc[3] = __hfma2(nq1, as_h2(hv1.w), __hmul2(nq0, as_h2(hv0.w)));
    // rare tail: cnt > 64
    for (int j = 64 + 2 * eo; j < cnt; j += 64) {
        uint ea = row[j];
        uint eb = row[((j + 1) < cnt) ? (j + 1) : 0];
        ushort qa = (ushort)(ea >> 17);
        ushort qb = ((j + 1) < cnt) ? (ushort)(eb >> 17) : (ushort)0;
        __half2 na = __half2half2(__ushort_as_half(qa));
        __half2 nb = __half2half2(__ushort_as_half(qb));
        int sa = ea & 0x1FFFF, sb = eb & 0x1FFFF;
        uint4 ha = *(const uint4*)(x16 + (size_t)sa * 16 + c2 * 8);
        uint4 hb = *(const uint4*)(x16 + (size_t)sb * 16 + c2 * 8);
        acc[0] = __hfma2(nb, as_h2(hb.x), __hfma2(na, as_h2(ha.x), acc[0]));
        acc[1] = __hfma2(nb, as_h2(hb.y), __hfma2(na, as_h2(ha.y), acc[1]));
        acc[2] = __hfma2(nb, as_h2(hb.z), __hfma2(na, as_h2(ha.z), acc[2]));
        acc[3] = __hfma2(nb, as_h2(hb.w), __hfma2(na, as_h2(ha.w), acc[3]));
    }
#pragma unroll
    for (int m = 2; m < 64; m <<= 1) {
#pragma unroll
        for (int k = 0; k < 4; k++)
            acc[k] = __hadd2(acc[k], as_h2(__shfl_xor(as_u32(acc[k]), m, 64)));
    }
    if (lane < 2) {
        float accf[8];
#pragma unroll
        for (int k = 0; k < 4; k++) {
            float2 f = __half22float2(acc[k]);
            accf[2 * k + 0] = f.x;
            accf[2 * k + 1] = f.y;
        }
        uint4 hv = *(const uint4*)(x16 + (size_t)node * 16 + c2 * 8);
        float2 s0f = __half22float2(as_h2(hv.x));
        float2 s1f = __half22float2(as_h2(hv.y));
        float2 s2f = __half22float2(as_h2(hv.z));
        float2 s3f = __half22float2(as_h2(hv.w));
        float slf[8] = {s0f.x, s0f.y, s1f.x, s1f.y, s2f.x, s2f.y, s3f.x, s3f.y};
        float r[8];
#pragma unroll
        for (int k = 0; k < 8; k++) r[k] = accf[k] + di * slf[k];
        int ns = *spill_cnt;                       // 0 in practice
        if (ns > 0) {
            if (ns > SPILL_MAX) ns = SPILL_MAX;
            for (int i = 0; i < ns; i++) {
                int4 q = sp[i];
                if (q.y == node) {
                    float f = dinv[q.x] * __int_as_float(q.z);
                    uint4 qv = *(const uint4*)(x16 + (size_t)q.x * 16 + c2 * 8);
                    float2 u0 = __half22float2(as_h2(qv.x));
                    float2 u1 = __half22float2(as_h2(qv.y));
                    float2 u2 = __half22float2(as_h2(qv.z));
                    float2 u3 = __half22float2(as_h2(qv.w));
                    float uv[8] = {u0.x, u0.y, u1.x, u1.y, u2.x, u2.y, u3.x, u3.y};
                    for (int k = 0; k < 8; k++) r[k] += f * uv[k];
                }
            }
        }
#pragma unroll
        for (int k = 0; k < 8; k++) fvs[wave][c2 * 8 + k] = r[k] * di;
    }
    __syncthreads();
    float fv[16];
#pragma unroll
    for (int k = 0; k < 16; k++) fv[k] = fvs[wave][k];
    float a = b1[2 * lane], bb = b1[2 * lane + 1];
#pragma unroll
    for (int k = 0; k < 16; k++) {
        float2 wv = *(const float2*)(W1 + k * 128 + 2 * lane);
        a = fmaf(fv[k], wv.x, a);
        bb = fmaf(fv[k], wv.y, bb);
    }
    o1s[wave][2 * lane + 0] = fmaxf(a, 0.0f);
    o1s[wave][2 * lane + 1] = fmaxf(bb, 0.0f);
    __syncthreads();
    int c = lane & 15, g = lane >> 4;
    float p = 0.0f;
#pragma unroll
    for (int k = 0; k < 32; k++) {
        int kk = g * 32 + k;
        p = fmaf(o1s[wave][kk], W2[kk * 16 + c], p);
    }
    p += __shfl_down(p, 16, 64);
    p += __shfl_down(p, 32, 64);
    if (lane < 16) {
        h2[(size_t)node * 16 + c] = __float2half(p);
        out[(size_t)node * 16 + c] = di * di * p + b2[c];
    }
}

// layer-2 gather: out[node] += di * (sum q*h2[s] + spill); packed fp16 math.
__global__ __launch_bounds__(256) void k_gather2(const uint* __restrict__ sbuf,
                                                 const int2* __restrict__ meta,
                                                 const int4* __restrict__ sp,
                                                 const int* __restrict__ spill_cnt,
                                                 const float* __restrict__ dinv,
                                                 const __half* __restrict__ h2,
                                                 float* __restrict__ out) {
    int wave = threadIdx.x >> 6, lane = threadIdx.x & 63;
    int node = (blockIdx.x & 7) * NPX + (blockIdx.x >> 3) * 4 + wave;
    int c2 = lane & 1, eo = lane >> 1;
    int2 mm = meta[node];
    int beg = mm.x, cnt = mm.y;
    float di = dinv[node];
    const uint* row = sbuf + beg;
    int j0 = 2 * eo, j1 = 2 * eo + 1;
    uint e0 = row[(j0 < cnt) ? j0 : 0];
    uint e1 = row[(j1 < cnt) ? j1 : 0];
    ushort qb0 = (j0 < cnt) ? (ushort)(e0 >> 17) : (ushort)0;
    ushort qb1 = (j1 < cnt) ? (ushort)(e1 >> 17) : (ushort)0;
    __half2 nq0 = __half2half2(__ushort_as_half(qb0));
    __half2 nq1 = __half2half2(__ushort_as_half(qb1));
    int s0 = e0 & 0x1FFFF, s1 = e1 & 0x1FFFF;
    uint4 hv0 = *(const uint4*)(h2 + (size_t)s0 * 16 + c2 * 8);
    uint4 hv1 = *(const uint4*)(h2 + (size_t)s1 * 16 + c2 * 8);
    __half2 acc[4];
    acc[0] = __hfma2(nq1, as_h2(hv1.x), __hmul2(nq0, as_h2(hv0.x)));
    acc[1] = __hfma2(nq1, as_h2(hv1.y), __hmul2(nq0, as_h2(hv0.y)));
    acc[2] = __hfma2(nq1, as_h2(hv1.z), __hmul2(nq0, as_h2(hv0.z)));
    acc[3] = __hfma2(nq1, as_h2(hv1.w), __hmul2(nq0, as_h2(hv0.w)));
    for (int j = 64 + 2 * eo; j < cnt; j += 64) {
        uint ea = row[j];
        uint eb = row[((j + 1) < cnt) ? (j + 1) : 0];
        ushort qa = (ushort)(ea >> 17);
        ushort qb = ((j + 1) < cnt) ? (ushort)(eb >> 17) : (ushort)0;
        __half2 na = __half2half2(__ushort_as_half(qa));
        __half2 nb = __half2half2(__ushort_as_half(qb));
        int sa = ea & 0x1FFFF, sb = eb & 0x1FFFF;
        uint4 ha = *(const uint4*)(h2 + (size_t)sa * 16 + c2 * 8);
        uint4 hb = *(const uint4*)(h2 + (size_t)sb * 16 + c2 * 8);
        acc[0] = __hfma2(nb, as_h2(hb.x), __hfma2(na, as_h2(ha.x), acc[0]));
        acc[1] = __hfma2(nb, as_h2(hb.y), __hfma2(na, as_h2(ha.y), acc[1]));
        acc[2] = __hfma2(nb, as_h2(hb.z), __hfma2(na, as_h2(ha.z), acc[2]));
        acc[3] = __hfma2(nb, as_h2(hb.w), __hfma2(na, as_h2(ha.w), acc[3]));
    }
#pragma unroll
    for (int m = 2; m < 64; m <<= 1) {
#pragma unroll
        for (int k = 0; k < 4; k++)
            acc[k] = __hadd2(acc[k], as_h2(__shfl_xor(as_u32(acc[k]), m, 64)));
    }
    if (lane < 2) {
        float accf[8];
#pragma unroll
        for (int k = 0; k < 4; k++) {
            float2 f = __half22float2(acc[k]);
            accf[2 * k + 0] = f.x;
            accf[2 * k + 1] = f.y;
        }
        int ns = *spill_cnt;
        if (ns > 0) {
            if (ns > SPILL_MAX) ns = SPILL_MAX;
            for (int i = 0; i < ns; i++) {
                int4 q = sp[i];
                if (q.y == node) {
                    float f = dinv[q.x] * __int_as_float(q.z);
                    uint4 qv = *(const uint4*)(h2 + (size_t)q.x * 16 + c2 * 8);
                    float2 u0 = __half22float2(as_h2(qv.x));
                    float2 u1 = __half22float2(as_h2(qv.y));
                    float2 u2 = __half22float2(as_h2(qv.z));
                    float2 u3 = __half22float2(as_h2(qv.w));
                    float uv[8] = {u0.x, u0.y, u1.x, u1.y, u2.x, u2.y, u3.x, u3.y};
                    for (int k = 0; k < 8; k++) accf[k] += f * uv[k];
                }
            }
        }
        float4* op = (float4*)(out + (size_t)node * 16 + c2 * 8);
        float4 o0 = op[0], o1 = op[1];
        o0.x += di * accf[0]; o0.y += di * accf[1];
        o0.z += di * accf[2]; o0.w += di * accf[3];
        o1.x += di * accf[4]; o1.y += di * accf[5];
        o1.z += di * accf[6]; o1.w += di * accf[7];
        op[0] = o0; op[1] = o1;
    }
}

// ===================== CSR fallback (round-2) =====================

__global__ void k_init(float* __restrict__ deg, int* __restrict__ cnt) {
    int i = blockIdx.x * blockDim.x + threadIdx.x;
    if (i < N_NODES) { deg[i] = 1.0f; if (cnt) cnt[i] = 0; }
}

__global__ void k_degcnt(const int* __restrict__ dst, const float* __restrict__ w,
                         float* __restrict__ deg, int* __restrict__ cnt) {
    int e = blockIdx.x * blockDim.x + threadIdx.x;
    if (e < N_EDGES) {
        int d = dst[e];
        atomicAdd(&deg[d], w[e]);
        if (cnt) atomicAdd(&cnt[d], 1);
    }
}

__global__ void k_dinv_agg(const float* __restrict__ x, float* __restrict__ deg_dinv,
                           float* __restrict__ agg) {
    int i = blockIdx.x * blockDim.x + threadIdx.x;
    if (i >= N_NODES) return;
    float di = rsqrtf(deg_dinv[i]);
    deg_dinv[i] = di;
    float s = di * di;
    const float4* xr = (const float4*)(x + (size_t)i * 16);
    float4* ar = (float4*)(agg + (size_t)i * 16);
#pragma unroll
    for (int k = 0; k < 4; k++) {
        float4 v = xr[k];
        v.x *= s; v.y *= s; v.z *= s; v.w *= s;
        ar[k] = v;
    }
}

__global__ __launch_bounds__(256) void k_scan1(const int* __restrict__ cnt,
                                               int* __restrict__ rowptr,
                                               int* __restrict__ bsum) {
    __shared__ int ts[256];
    int tid = threadIdx.x;
    int base = blockIdx.x * SCAN_CHUNK + tid * 8;
    int v[8]; int s = 0;
#pragma unroll
    for (int k = 0; k < 8; k++) {
        int idx = base + k;
        v[k] = (idx < N_NODES) ? cnt[idx] : 0;
        s += v[k];
    }
    ts[tid] = s;
    __syncthreads();
    for (int off = 1; off < 256; off <<= 1) {
        int t = (tid >= off) ? ts[tid - off] : 0;
        __syncthreads();
        ts[tid] += t;
        __syncthreads();
    }
    int run = ts[tid] - s;
#pragma unroll
    for (int k = 0; k < 8; k++) {
        int idx = base + k;
        if (idx < N_NODES) rowptr[idx] = run;
        run += v[k];
    }
    if (tid == 255) bsum[blockIdx.x] = ts[255];
}

__global__ void k_scan2(int* __restrict__ bsum) {
    if (threadIdx.x == 0 && blockIdx.x == 0) {
        int run = 0;
        for (int g = 0; g < SCAN_BLOCKS; g++) { int t = bsum[g]; bsum[g] = run; run += t; }
    }
}

__global__ __launch_bounds__(256) void k_scan3(int* __restrict__ rowptr,
                                               const int* __restrict__ bsum) {
    int tid = threadIdx.x;
    int base = blockIdx.x * SCAN_CHUNK + tid * 8;
    int off = bsum[blockIdx.x];
#pragma unroll
    for (int k = 0; k < 8; k++) {
        int idx = base + k;
        if (idx < N_NODES) rowptr[idx] += off;
    }
    if (blockIdx.x == 0 && tid == 0) rowptr[N_NODES] = N_EDGES;
}

__global__ void k_fill(const int* __restrict__ src, const int* __restrict__ dst,
                       const float* __restrict__ w, const float* __restrict__ dinv,
                       const int* __restrict__ rowptr, int* __restrict__ cnt,
                       int2* __restrict__ perm) {
    int e = blockIdx.x * blockDim.x + threadIdx.x;
    if (e >= N_EDGES) return;
    int s = src[e], d = dst[e];
    float nrm = dinv[s] * w[e] * dinv[d];
    int r = atomicSub(&cnt[d], 1) - 1;
    int pos = rowptr[d] + r;
    perm[pos] = make_int2(s, __float_as_int(nrm));
}

__global__ __launch_bounds__(256) void k_gather(const int2* __restrict__ perm,
                                                const int* __restrict__ rowptr,
                                                const float* __restrict__ feat,
                                                float* __restrict__ out) {
    int wave = threadIdx.x >> 6, lane = threadIdx.x & 63;
    int node = blockIdx.x * 4 + wave;
    int c = lane & 15, eo = lane >> 4;
    int beg = rowptr[node], end = rowptr[node + 1];
    float acc = 0.0f;
    for (int j = beg + eo; j < end; j += 4) {
        int2 ed = perm[j];
        acc = fmaf(__int_as_float(ed.y), feat[(size_t)ed.x * 16 + c], acc);
    }
    acc += __shfl_xor(acc, 16, 64);
    acc += __shfl_xor(acc, 32, 64);
    if (lane < 16) out[(size_t)node * 16 + c] += acc;
}

__global__ __launch_bounds__(256) void k_mlp(float* __restrict__ agg,
                                             const float* __restrict__ W1,
                                             const float* __restrict__ b1,
                                             const float* __restrict__ W2,
                                             const float* __restrict__ b2,
                                             const float* __restrict__ dinv,
                                             float* __restrict__ out) {
    __shared__ float o1s[4][128];
    int wave = threadIdx.x >> 6;
    int lane = threadIdx.x & 63;
    int node = blockIdx.x * 4 + wave;
    const float* f = agg + (size_t)node * 16;
    float fv[16];
#pragma unroll
    for (int k = 0; k < 4; k++) {
        float4 v = ((const float4*)f)[k];
        fv[4 * k + 0] = v.x; fv[4 * k + 1] = v.y; fv[4 * k + 2] = v.z; fv[4 * k + 3] = v.w;
    }
    float a = b1[2 * lane], b = b1[2 * lane + 1];
#pragma unroll
    for (int k = 0; k < 16; k++) {
        float2 wv = *(const float2*)(W1 + k * 128 + 2 * lane);
        a = fmaf(fv[k], wv.x, a);
        b = fmaf(fv[k], wv.y, b);
    }
    o1s[wave][2 * lane + 0] = fmaxf(a, 0.0f);
    o1s[wave][2 * lane + 1] = fmaxf(b, 0.0f);
    __syncthreads();
    int c = lane & 15, g = lane >> 4;
    float p = 0.0f;
#pragma unroll
    for (int k = 0; k < 32; k++) {
        int kk = g * 32 + k;
        p = fmaf(o1s[wave][kk], W2[kk * 16 + c], p);
    }
    p += __shfl_down(p, 16, 64);
    p += __shfl_down(p, 32, 64);
    __syncthreads();
    if (lane < 16) {
        float h2v = p;
        agg[(size_t)node * 16 + c] = h2v;
        float di = dinv[node];
        out[(size_t)node * 16 + c] = di * di * h2v + b2[c];
    }
}

__global__ void k_scatter(const int* __restrict__ src, const int* __restrict__ dst,
                          const float* __restrict__ w, const float* __restrict__ dinv,
                          const float* __restrict__ feat, float* __restrict__ out) {
    int t = blockIdx.x * blockDim.x + threadIdx.x;
    int e = t >> 2;
    int c4 = (t & 3) * 4;
    if (e >= N_EDGES) return;
    int s = src[e], d = dst[e];
    float nrm = dinv[s] * w[e] * dinv[d];
    float4 v = *(const float4*)(feat + (size_t)s * 16 + c4);
    float* o = out + (size_t)d * 16 + c4;
    atomicAdd(o + 0, nrm * v.x);
    atomicAdd(o + 1, nrm * v.y);
    atomicAdd(o + 2, nrm * v.z);
    atomicAdd(o + 3, nrm * v.w);
}

// ===================== launch =====================

extern "C" void kernel_launch(void* const* d_in, const int* in_sizes, int n_in,
                              void* d_out, int out_size, void* d_ws, size_t ws_size,
                              hipStream_t stream) {
    const float* x  = (const float*)d_in[0];
    const int*   ei = (const int*)d_in[1];
    const float* w  = (const float*)d_in[2];
    const float* W1 = (const float*)d_in[3];
    const float* b1 = (const float*)d_in[4];
    const float* W2 = (const float*)d_in[5];
    const float* b2 = (const float*)d_in[6];
    float* out = (float*)d_out;

    const int* src = ei;
    const int* dst = ei + N_EDGES;
    const int B = 256;

    // ---- fast-path workspace layout (16B-aligned blocks) ----
    char* p = (char*)d_ws;
    int*    bucket_cnt = (int*)p;        p += (size_t)((NBUCK + 3) & ~3) * 4;
    int*    spill_cnt  = (int*)p;        p += 16;
    float*  dinv       = (float*)p;      p += (size_t)N_PAD * 4;
    int2*   meta       = (int2*)p;       p += (size_t)N_PAD * 8;
    __half* x16        = (__half*)p;     p += (size_t)N_NODES * 16 * 2;
    __half* h2         = (__half*)p;     p += (size_t)N_NODES * 16 * 2;
    int4*   sp         = (int4*)p;       p += (size_t)SPILL_MAX * 16;
    uint2*  ebuf       = (uint2*)p;      p += (size_t)NBUCK * BCAP * 8;
    const size_t WS_FAST = (size_t)(p - (char*)d_ws);

    if (ws_size >= WS_FAST) {
        k_pre<<<(N_NODES * 16 + B - 1) / B, B, 0, stream>>>(x, x16, bucket_cnt, spill_cnt);
        k_bin<<<BIN_BLOCKS, B, 0, stream>>>(src, dst, w, bucket_cnt, ebuf, sp, spill_cnt);
        k_sort<<<NBUCK, B, 0, stream>>>(ebuf, bucket_cnt, sp, spill_cnt, dinv, meta);
        k_nrm<<<NBUCK, B, 0, stream>>>((uint*)ebuf, bucket_cnt, dinv);
        k_gather_mlp<<<N_NODES / 4, B, 0, stream>>>((const uint*)ebuf, meta,
                                                    sp, spill_cnt, dinv, x16,
                                                    W1, b1, W2, b2, h2, out);
        k_gather2<<<N_NODES / 4, B, 0, stream>>>((const uint*)ebuf, meta,
                                                 sp, spill_cnt, dinv, h2, out);
        return;
    }

    // ---- CSR fallback (round-2 path) ----
    float* deg_dinv = (float*)d_ws;
    int*   cntb     = (int*)(deg_dinv + N_PAD);
    int*   rowptr   = cntb + N_PAD;
    int*   bsum     = rowptr + N_PAD;
    float* agg      = (float*)(bsum + 64);
    int2*  perm     = (int2*)(agg + (size_t)N_NODES * 16);
    const size_t WS_CSR = ((size_t)N_PAD * 3 + 64 + (size_t)N_NODES * 16) * 4
                          + (size_t)N_EDGES * 8;

    if (ws_size >= WS_CSR) {
        k_init<<<(N_NODES + B - 1) / B, B, 0, stream>>>(deg_dinv, cntb);
        k_degcnt<<<(N_EDGES + B - 1) / B, B, 0, stream>>>(dst, w, deg_dinv, cntb);
        k_dinv_agg<<<(N_NODES + B - 1) / B, B, 0, stream>>>(x, deg_dinv, agg);
        k_scan1<<<SCAN_BLOCKS, 256, 0, stream>>>(cntb, rowptr, bsum);
        k_scan2<<<1, 64, 0, stream>>>(bsum);
        k_scan3<<<SCAN_BLOCKS, 256, 0, stream>>>(rowptr, bsum);
        k_fill<<<(N_EDGES + B - 1) / B, B, 0, stream>>>(src, dst, w, deg_dinv,
                                                        rowptr, cntb, perm);
        k_gather<<<N_NODES / 4, B, 0, stream>>>(perm, rowptr, x, agg);
        k_mlp<<<N_NODES / 4, B, 0, stream>>>(agg, W1, b1, W2, b2, deg_dinv, out);
        k_gather<<<N_NODES / 4, B, 0, stream>>>(perm, rowptr, agg, out);
    } else {
        float* deg = (float*)d_ws;
        float* ag  = (float*)d_ws + N_NODES;
        k_init<<<(N_NODES + B - 1) / B, B, 0, stream>>>(deg, (int*)nullptr);
        k_degcnt<<<(N_EDGES + B - 1) / B, B, 0, stream>>>(dst, w, deg, (int*)nullptr);
        k_dinv_agg<<<(N_NODES + B - 1) / B, B, 0, stream>>>(x, deg, ag);
        k_scatter<<<((size_t)N_EDGES * 4 + B - 1) / B, B, 0, stream>>>(src, dst, w, deg, x, ag);
        k_mlp<<<N_NODES / 4, B, 0, stream>>>(ag, W1, b1, W2, b2, deg, out);
        k_scatter<<<((size_t)N_EDGES * 4 + B - 1) / B, B, 0, stream>>>(src, dst, w, deg, ag, out);
    }
}